// Round 3
// baseline (354.999 us; speedup 1.0000x reference)
//
#include <hip/hip_runtime.h>
#include <hip/hip_fp16.h>

#define NN 50000
#define NE 800000
#define D 64
#define EPS 1e-5f
#define NT 3125   // NN/16 row-tiles for MFMA GEMMs
#define NB1 250   // partition blocks (NB1*EPB == NE)
#define EPB 3200  // edges per partition block
#define NBIN 196  // coarse bins = ceil(NN/256)
#define STOT 49152  // padded scan length (192*256 >= NBIN*NB1)
#define SBLK 192

typedef unsigned short ushort_t;
typedef unsigned int uint_t;
typedef __attribute__((ext_vector_type(8))) short bf16x8;
typedef __attribute__((ext_vector_type(4))) float f32x4;

__device__ __forceinline__ float wave_sum64(float v) {
#pragma unroll
  for (int m = 1; m <= 32; m <<= 1) v += __shfl_xor(v, m, 64);
  return v;
}
__device__ __forceinline__ int wave_sum64i(int v) {
#pragma unroll
  for (int m = 1; m <= 32; m <<= 1) v += __shfl_xor(v, m, 64);
  return v;
}
__device__ __forceinline__ float group_sum16(float v) {
#pragma unroll
  for (int m = 1; m <= 8; m <<= 1) v += __shfl_xor(v, m, 64);
  return v;
}
__device__ __forceinline__ float silu_f(float v) { return v / (1.f + __expf(-v)); }
__device__ __forceinline__ float lrelu_f(float v) { return v >= 0.f ? v : 0.2f * v; }
__device__ __forceinline__ ushort_t f2b(float x) {
  unsigned u = __float_as_uint(x);
  return (ushort_t)((u + 0x7FFFu + ((u >> 16) & 1u)) >> 16);
}
__device__ __forceinline__ float b2f(ushort_t u) {
  return __uint_as_float(((unsigned)u) << 16);
}
__device__ __forceinline__ ushort_t f2h(float x) {
  return __half_as_ushort(__float2half_rn(x));
}
__device__ __forceinline__ float h2f(unsigned u) {
  return __half2float(__ushort_as_half((ushort_t)(u & 0xFFFFu)));
}
__device__ __forceinline__ float sel4(float a, float b, float c, float d, int h) {
  float ab = (h & 1) ? b : a;
  float cd = (h & 1) ? d : c;
  return (h & 2) ? cd : ab;
}
__device__ __forceinline__ bf16x8 pack8(float4 a, float4 b) {
  bf16x8 r;
  r[0] = (short)f2b(a.x); r[1] = (short)f2b(a.y);
  r[2] = (short)f2b(a.z); r[3] = (short)f2b(a.w);
  r[4] = (short)f2b(b.x); r[5] = (short)f2b(b.y);
  r[6] = (short)f2b(b.z); r[7] = (short)f2b(b.w);
  return r;
}

// ---------- fused prep entry: hist (blocks 0..NB1-1) + layer0 dual GEMM ----------
__global__ void __launch_bounds__(256) k_pre(
    const int* __restrict__ ei, int* __restrict__ histG,
    const float* __restrict__ x, const float* __restrict__ W1,
    const float* __restrict__ W2, const float* __restrict__ b2,
    ushort_t* __restrict__ out1, float* __restrict__ out2) {
  __shared__ __align__(16) char smem[16384];
  if (blockIdx.x < NB1) {
    // coarse histogram role
    int* h = (int*)smem;
    int blk = blockIdx.x;
    for (int j = threadIdx.x; j < NBIN; j += 256) h[j] = 0;
    __syncthreads();
    int e0 = blk * EPB;
    for (int e = e0 + threadIdx.x; e < e0 + EPB; e += 256)
      atomicAdd(&h[ei[NE + e] >> 8], 1);
    __syncthreads();
    for (int j = threadIdx.x; j < NBIN; j += 256) histG[j * NB1 + blk] = h[j];
    return;
  }
  // layer-0 dual GEMM role (independent of prep)
  ushort_t* wf = (ushort_t*)smem;
  for (int e = threadIdx.x; e < 8192; e += 256) {
    int f = e >> 9, r = e & 511;
    int lane = r >> 3, j = r & 7;
    int m = f >> 3, s = (f >> 2) & 1, t = f & 3;
    int k = s * 32 + (lane >> 4) * 8 + j;
    int n = t * 16 + (lane & 15);
    const float* Wm = m ? W2 : W1;
    wf[e] = f2b(Wm[k * D + n]);
  }
  __syncthreads();
  int tile = (blockIdx.x - NB1) * 4 + (threadIdx.x >> 6);
  if (tile >= NT) return;
  int l = threadIdx.x & 63;
  int q = l >> 4, cn = l & 15;
  const float* xr = x + ((size_t)tile * 16 + cn) * D + q * 8;
  float4 xa = *(const float4*)xr;
  float4 xb = *(const float4*)(xr + 4);
  float4 xc = *(const float4*)(xr + 32);
  float4 xd = *(const float4*)(xr + 36);
  bf16x8 a0 = pack8(xa, xb), a1 = pack8(xc, xd);
  f32x4 acc1[4], acc2[4];
#pragma unroll
  for (int t = 0; t < 4; ++t) {
    bf16x8 b10 = *(const bf16x8*)&wf[(0 * 8 + 0 * 4 + t) * 512 + l * 8];
    bf16x8 b11 = *(const bf16x8*)&wf[(0 * 8 + 1 * 4 + t) * 512 + l * 8];
    bf16x8 b20 = *(const bf16x8*)&wf[(1 * 8 + 0 * 4 + t) * 512 + l * 8];
    bf16x8 b21 = *(const bf16x8*)&wf[(1 * 8 + 1 * 4 + t) * 512 + l * 8];
    f32x4 z = {0.f, 0.f, 0.f, 0.f};
    acc1[t] = __builtin_amdgcn_mfma_f32_16x16x32_bf16(a0, b10, z, 0, 0, 0);
    acc1[t] = __builtin_amdgcn_mfma_f32_16x16x32_bf16(a1, b11, acc1[t], 0, 0, 0);
    acc2[t] = __builtin_amdgcn_mfma_f32_16x16x32_bf16(a0, b20, z, 0, 0, 0);
    acc2[t] = __builtin_amdgcn_mfma_f32_16x16x32_bf16(a1, b21, acc2[t], 0, 0, 0);
  }
#pragma unroll
  for (int t = 0; t < 4; ++t) {
    float bb = b2[t * 16 + cn];
#pragma unroll
    for (int r = 0; r < 4; ++r) {
      size_t row = (size_t)tile * 16 + q * 4 + r;
      out1[row * D + t * 16 + cn] = f2b(acc1[t][r]);
      out2[row * D + t * 16 + cn] = acc2[t][r] + bb;
    }
  }
}

// ---------- scan A: block-local exclusive scan + block sums; block SBLK does
// one-time weight->fragment conversion, wea, scal/degsum zeroing ----------
__global__ void __launch_bounds__(256) k_scanA(
    int* __restrict__ histG, int* __restrict__ bsum, float* __restrict__ scal,
    const float* __restrict__ Wg0, const float* __restrict__ Wg1,
    const float* __restrict__ W11, const float* __restrict__ W21,
    const float* __restrict__ We0, const float* __restrict__ ae0,
    const float* __restrict__ We1, const float* __restrict__ ae1,
    ushort_t* __restrict__ wg16, ushort_t* __restrict__ wd16,
    float* __restrict__ wea2, float* __restrict__ degsum) {
  if (blockIdx.x == SBLK) {
    int tid = threadIdx.x;
    for (int t = tid; t < 1024; t += 256) scal[t] = 0.f;
    for (int t = tid; t < NN; t += 256) degsum[t] = 0.f;
    for (int e = tid; e < 4096; e += 256) {
      int f = e >> 9, r = e & 511;
      int lane = r >> 3, j = r & 7;
      int s = (f >> 2) & 1, t = f & 3;
      int k = s * 32 + (lane >> 4) * 8 + j;
      int n = t * 16 + (lane & 15);
      wg16[e] = f2b(Wg0[k * D + n]);
      wg16[4096 + e] = f2b(Wg1[k * D + n]);
    }
    for (int e = tid; e < 8192; e += 256) {
      int f = e >> 9, r = e & 511;
      int lane = r >> 3, j = r & 7;
      int m = f >> 3, s = (f >> 2) & 1, t = f & 3;
      int k = s * 32 + (lane >> 4) * 8 + j;
      int n = t * 16 + (lane & 15);
      const float* Wm = m ? W21 : W11;
      wd16[e] = f2b(Wm[k * D + n]);
    }
    if (tid < 64) {
      float v = group_sum16(We0[tid] * ae0[tid]);
      if ((tid & 15) == 0) wea2[tid >> 4] = v;
    } else if (tid < 128) {
      int c = tid - 64;
      float v = group_sum16(We1[c] * ae1[c]);
      if ((c & 15) == 0) wea2[4 + (c >> 4)] = v;
    }
    return;
  }
  __shared__ int sm[256];
  int j = threadIdx.x;
  int i = blockIdx.x * 256 + j;
  const int TOT = NBIN * NB1;
  int v = (i < TOT) ? histG[i] : 0;
  sm[j] = v;
  __syncthreads();
  for (int off = 1; off < 256; off <<= 1) {
    int t = (j >= off) ? sm[j - off] : 0;
    __syncthreads();
    sm[j] += t;
    __syncthreads();
  }
  if (i < TOT) histG[i] = sm[j] - v;  // block-local exclusive
  if (j == 255) bsum[blockIdx.x] = sm[255];
}

// ---------- scan C: each block derives its own prefix from raw bsum ----------
__global__ void __launch_bounds__(256) k_scanC(int* __restrict__ histG,
                                               const int* __restrict__ bsum) {
  __shared__ int ws4[4];
  int t = threadIdx.x;
  int v = (t < (int)blockIdx.x) ? bsum[t] : 0;
  v = wave_sum64i(v);
  if ((t & 63) == 0) ws4[t >> 6] = v;
  __syncthreads();
  int prefix = ws4[0] + ws4[1] + ws4[2] + ws4[3];
  int i = blockIdx.x * 256 + t;
  if (i < NBIN * NB1) histG[i] += prefix;
}

// Partition pass: scatter packed temp records, accumulate ea sum + deg sums.
__global__ void __launch_bounds__(256) k_part(
    const int* __restrict__ ei, const float* __restrict__ ew,
    const float* __restrict__ ea, const int* __restrict__ histG,
    uint2* __restrict__ rectmp, float* __restrict__ scal,
    float* __restrict__ degsum) {
  __shared__ int cur[NBIN];
  int blk = blockIdx.x;
  for (int j = threadIdx.x; j < NBIN; j += 256) cur[j] = histG[j * NB1 + blk];
  __syncthreads();
  int e0 = blk * EPB;
  float asum = 0.f;
  for (int e = e0 + threadIdx.x; e < e0 + EPB; e += 256) {
    int src = ei[e];
    int dst = ei[NE + e];
    float w = ew[e];
    float a = ea[e];
    asum += a;
    atomicAdd(&degsum[dst], w);
    int slot = atomicAdd(&cur[dst >> 8], 1);
    uint2 r;
    r.x = (uint_t)(src & 0xFFFF) | ((uint_t)f2h(w) << 16);
    r.y = (uint_t)(dst & 0xFF) | ((uint_t)f2h(a) << 16);
    rectmp[slot] = r;
  }
  float s = wave_sum64(asum);
  if ((threadIdx.x & 63) == 0) {
    int slot = (blk * 4 + (threadIdx.x >> 6)) & 63;
    atomicAdd(&scal[(size_t)slot * 16], s);
  }
}

// Final counting sort within each coarse bucket; emits rs[], dinv[], and
// per-edge records with PRECOMPUTED f32 GCN norm (layer-invariant):
//   recw = {src, f32 norm}, reca = src | f16(ea)<<16
__global__ void __launch_bounds__(256) k_sfin(
    const uint2* __restrict__ rectmp, const int* __restrict__ histG,
    uint2* __restrict__ recw, uint_t* __restrict__ reca, int* __restrict__ rs,
    float* __restrict__ dinv, const float* __restrict__ degsum,
    float* __restrict__ scal) {
  __shared__ int cnt[256], sc[256], cur[256];
  __shared__ float dinvl[256];
  int b = blockIdx.x;
  int t = threadIdx.x;
  int lo = histG[b * NB1];
  int hi = (b == NBIN - 1) ? NE : histG[(b + 1) * NB1];
  cnt[t] = 0;
  __syncthreads();
  for (int e = lo + t; e < hi; e += 256)
    atomicAdd(&cnt[rectmp[e].y & 0xFFu], 1);
  __syncthreads();
  int v = cnt[t];
  sc[t] = v;
  __syncthreads();
  for (int off = 1; off < 256; off <<= 1) {
    int u = (t >= off) ? sc[t - off] : 0;
    __syncthreads();
    sc[t] += u;
    __syncthreads();
  }
  int ex = sc[t] - v;  // exclusive within bucket
  int node = b * 256 + t;
  float dloc = (node < NN) ? rsqrtf(1.f + degsum[node]) : 0.f;
  dinvl[t] = dloc;
  if (node < NN) {
    rs[node] = lo + ex;
    dinv[node] = dloc;
  }
  if (b == NBIN - 1 && t == 0) rs[NN] = NE;
  cur[t] = lo + ex;
  __syncthreads();
  for (int e = lo + t; e < hi; e += 256) {
    uint2 r = rectmp[e];
    int dl = (int)(r.y & 0xFFu);
    int slot = atomicAdd(&cur[dl], 1);
    uint_t src = r.x & 0xFFFFu;
    float w = h2f(r.x >> 16);
    float norm = rsqrtf(1.f + degsum[src]) * w * dinvl[dl];
    uint2 o;
    o.x = src;
    o.y = __float_as_uint(norm);
    recw[slot] = o;
    reca[slot] = src | (r.y & 0xFFFF0000u);
  }
  if (b == 0 && t == 0) {
    float s = 0.f;
    for (int j = 0; j < 64; ++j) s += scal[(size_t)j * 16];
    scal[1] = s / (float)NE;
  }
}

// ---------- fused GCN aggregate + LN + GAT node transform ----------
// 4 waves/block, 2 nodes/wave -> 8 nodes/block; MFMA tile rows 8..15 zeroed.
__global__ void __launch_bounds__(256) k_gcn_gat(
    const ushort_t* __restrict__ h16, const float* __restrict__ res,
    const float* __restrict__ dinv, const int* __restrict__ rs,
    const uint2* __restrict__ recw,
    const float* __restrict__ gb, const float* __restrict__ lg,
    const float* __restrict__ lb,
    const ushort_t* __restrict__ wg, const float* __restrict__ att_src,
    const float* __restrict__ att_dst,
    float* __restrict__ x2, ushort_t* __restrict__ xl,
    float* __restrict__ a_s, float* __restrict__ a_d) {
  __shared__ int ss[4][64];
  __shared__ float swt[4][64];
  __shared__ __align__(16) ushort_t xt[16][72];  // 144B row stride
  int w = threadIdx.x >> 6;
  int l = threadIdx.x & 63;
  int base = blockIdx.x * 8;
  int iA = base + 2 * w;
  int iB = iA + 1;
  int half = l >> 5, cp = l & 31;
  float diA = dinv[iA], diB = dinv[iB];
  float accA = diA * diA * b2f(h16[(size_t)iA * D + l]);
  float accB = diB * diB * b2f(h16[(size_t)iB * D + l]);
  int kA = rs[iA], kA1 = rs[iA + 1];
  int kB = rs[iB], kB1 = rs[iB + 1];
  while (kA < kA1 || kB < kB1) {
    int cntA = min(32, kA1 - kA);
    int cntB = min(32, kB1 - kB);
    int src = 0; float wn = 0.f;
    if (half == 0) {
      if (cp < cntA) {
        uint2 r = recw[(size_t)(kA + cp)];
        src = (int)r.x;
        wn = __uint_as_float(r.y);
      }
    } else {
      if (cp < cntB) {
        uint2 r = recw[(size_t)(kB + cp)];
        src = (int)r.x;
        wn = __uint_as_float(r.y);
      }
    }
    ss[w][l] = src;
    swt[w][l] = wn;
    int nm = max(cntA, cntB);
    int j = 0;
    for (; j + 4 <= nm; j += 4) {
      int4 sa = *(const int4*)&ss[w][j];
      int4 sb = *(const int4*)&ss[w][32 + j];
      float4 wa = *(const float4*)&swt[w][j];
      float4 wb = *(const float4*)&swt[w][32 + j];
      float a0 = b2f(h16[(size_t)sa.x * D + l]);
      float b0 = b2f(h16[(size_t)sb.x * D + l]);
      float a1 = b2f(h16[(size_t)sa.y * D + l]);
      float b1 = b2f(h16[(size_t)sb.y * D + l]);
      float a2 = b2f(h16[(size_t)sa.z * D + l]);
      float b2v = b2f(h16[(size_t)sb.z * D + l]);
      float a3 = b2f(h16[(size_t)sa.w * D + l]);
      float b3 = b2f(h16[(size_t)sb.w * D + l]);
      accA = fmaf(wa.x, a0, accA); accB = fmaf(wb.x, b0, accB);
      accA = fmaf(wa.y, a1, accA); accB = fmaf(wb.y, b1, accB);
      accA = fmaf(wa.z, a2, accA); accB = fmaf(wb.z, b2v, accB);
      accA = fmaf(wa.w, a3, accA); accB = fmaf(wb.w, b3, accB);
    }
    for (; j < nm; ++j) {
      int sA = ss[w][j], sB = ss[w][32 + j];
      float wA = swt[w][j], wB = swt[w][32 + j];
      float vA = b2f(h16[(size_t)sA * D + l]);
      float vB = b2f(h16[(size_t)sB * D + l]);
      accA = fmaf(wA, vA, accA);
      accB = fmaf(wB, vB, accB);
    }
    kA += cntA; kB += cntB;
  }
  float gbv = gb[l], lgv = lg[l], lbv = lb[l];
  float x1A = silu_f(accA + gbv) + res[(size_t)iA * D + l];
  float x1B = silu_f(accB + gbv) + res[(size_t)iB * D + l];
  float muA = wave_sum64(x1A) * (1.f / 64.f);
  float muB = wave_sum64(x1B) * (1.f / 64.f);
  float dA = x1A - muA, dB = x1B - muB;
  float varA = wave_sum64(dA * dA) * (1.f / 64.f);
  float varB = wave_sum64(dB * dB) * (1.f / 64.f);
  float oA = dA * rsqrtf(varA + EPS) * lgv + lbv;
  float oB = dB * rsqrtf(varB + EPS) * lgv + lbv;
  x2[(size_t)iA * D + l] = oA;
  x2[(size_t)iB * D + l] = oB;
  xt[2 * w][l] = f2b(oA);
  xt[2 * w + 1][l] = f2b(oB);
  {
    ushort_t* xz = &xt[8][0];
    for (int e = threadIdx.x; e < 8 * 72; e += 256) xz[e] = 0;
  }
  __syncthreads();
  // GAT node transform: xl = bf16(x2) @ Wg (wave w owns col-tile t=w)
  int t = w;
  int q = l >> 4, cn = l & 15;
  bf16x8 a0 = *(const bf16x8*)&xt[cn][q * 8];
  bf16x8 a1 = *(const bf16x8*)&xt[cn][q * 8 + 32];
  bf16x8 b0 = *(const bf16x8*)&wg[(size_t)((0 * 4 + t) * 512 + l * 8)];
  bf16x8 b1 = *(const bf16x8*)&wg[(size_t)((1 * 4 + t) * 512 + l * 8)];
  f32x4 z = {0.f, 0.f, 0.f, 0.f};
  f32x4 acc = __builtin_amdgcn_mfma_f32_16x16x32_bf16(a0, b0, z, 0, 0, 0);
  acc = __builtin_amdgcn_mfma_f32_16x16x32_bf16(a1, b1, acc, 0, 0, 0);
  if (q < 2) {  // only rows 0..7 are real nodes
    float av = att_src[t * 16 + cn];
    float dv = att_dst[t * 16 + cn];
#pragma unroll
    for (int r = 0; r < 4; ++r) {
      size_t row = (size_t)base + q * 4 + r;
      xl[row * D + t * 16 + cn] = f2b(acc[r]);
      float vs = group_sum16(acc[r] * av);
      float vd = group_sum16(acc[r] * dv);
      if (cn == 0) {
        a_s[row * 4 + t] = vs;
        a_d[row * 4 + t] = vd;
      }
    }
  }
}

// ---------- fused GAT aggregate (+ optional next-layer dual GEMM) ----------
template <int FUSE>
__global__ void __launch_bounds__(256) k_gat_fin(
    const ushort_t* __restrict__ xl16, const float* __restrict__ x2,
    const float* __restrict__ a_s, const float* __restrict__ a_d,
    const int* __restrict__ rs, const uint_t* __restrict__ reca,
    const float* __restrict__ wea, const float* __restrict__ scal,
    const float* __restrict__ bg,
    const ushort_t* __restrict__ wd, const float* __restrict__ b2,
    ushort_t* __restrict__ out1, float* __restrict__ out2,
    float* __restrict__ xout) {
  __shared__ int ss[4][64];
  __shared__ float el[4][4][68];
  __shared__ __align__(16) ushort_t xt[16][72];
  int w = threadIdx.x >> 6;
  int base = blockIdx.x * 8;
  int iA = base + 2 * w;
  int iB = iA + 1;
  int l = threadIdx.x & 63;
  int half = l >> 5, cp = l & 31;
  int hh = l >> 4;
  float4 wv4 = *(const float4*)wea;
  float mean_attr = scal[1];
  float we_h = sel4(wv4.x, wv4.y, wv4.z, wv4.w, hh);
  float ad_hA = a_d[(size_t)iA * 4 + hh], as_iA = a_s[(size_t)iA * 4 + hh];
  float ad_hB = a_d[(size_t)iB * 4 + hh], as_iB = a_s[(size_t)iB * 4 + hh];
  float eSA = __expf(lrelu_f(as_iA + ad_hA + mean_attr * we_h));
  float eSB = __expf(lrelu_f(as_iB + ad_hB + mean_attr * we_h));
  float sA = eSA, sB = eSB;
  float accA = eSA * b2f(xl16[(size_t)iA * D + l]);
  float accB = eSB * b2f(xl16[(size_t)iB * D + l]);
  const float* adp = a_d + (size_t)(half ? iB : iA) * 4;
  float4 ad4 = *(const float4*)adp;
  int kA = rs[iA], kA1 = rs[iA + 1];
  int kB = rs[iB], kB1 = rs[iB + 1];
  while (kA < kA1 || kB < kB1) {
    int cntA = min(32, kA1 - kA);
    int cntB = min(32, kB1 - kB);
    int myk = half ? kB : kA;
    int mycnt = half ? cntB : cntA;
    int src = 0;
    float e0v = 0.f, e1v = 0.f, e2v = 0.f, e3v = 0.f;
    if (cp < mycnt) {
      uint_t r = reca[(size_t)(myk + cp)];
      src = (int)(r & 0xFFFFu);
      float ea = h2f(r >> 16);
      float4 as4 = *(const float4*)(a_s + (size_t)src * 4);
      e0v = __expf(lrelu_f(as4.x + fmaf(ea, wv4.x, ad4.x)));
      e1v = __expf(lrelu_f(as4.y + fmaf(ea, wv4.y, ad4.y)));
      e2v = __expf(lrelu_f(as4.z + fmaf(ea, wv4.z, ad4.z)));
      e3v = __expf(lrelu_f(as4.w + fmaf(ea, wv4.w, ad4.w)));
    }
    ss[w][l] = src;
    el[w][0][l] = e0v;
    el[w][1][l] = e1v;
    el[w][2][l] = e2v;
    el[w][3][l] = e3v;
    int nm = max(cntA, cntB);
    int j = 0;
    for (; j + 4 <= nm; j += 4) {
      int4 sa = *(const int4*)&ss[w][j];
      int4 sb = *(const int4*)&ss[w][32 + j];
      float4 ea4 = *(const float4*)&el[w][hh][j];
      float4 eb4 = *(const float4*)&el[w][hh][32 + j];
      float a0 = b2f(xl16[(size_t)sa.x * D + l]);
      float b0 = b2f(xl16[(size_t)sb.x * D + l]);
      float a1 = b2f(xl16[(size_t)sa.y * D + l]);
      float b1 = b2f(xl16[(size_t)sb.y * D + l]);
      float a2 = b2f(xl16[(size_t)sa.z * D + l]);
      float b2v = b2f(xl16[(size_t)sb.z * D + l]);
      float a3 = b2f(xl16[(size_t)sa.w * D + l]);
      float b3 = b2f(xl16[(size_t)sb.w * D + l]);
      accA = fmaf(ea4.x, a0, accA); accB = fmaf(eb4.x, b0, accB);
      accA = fmaf(ea4.y, a1, accA); accB = fmaf(eb4.y, b1, accB);
      accA = fmaf(ea4.z, a2, accA); accB = fmaf(eb4.z, b2v, accB);
      accA = fmaf(ea4.w, a3, accA); accB = fmaf(eb4.w, b3, accB);
      sA += (ea4.x + ea4.y) + (ea4.z + ea4.w);
      sB += (eb4.x + eb4.y) + (eb4.z + eb4.w);
    }
    for (; j < nm; ++j) {
      int srcA = ss[w][j], srcB = ss[w][32 + j];
      float eA = el[w][hh][j], eB = el[w][hh][32 + j];
      float vA = b2f(xl16[(size_t)srcA * D + l]);
      float vB = b2f(xl16[(size_t)srcB * D + l]);
      accA = fmaf(eA, vA, accA);
      accB = fmaf(eB, vB, accB);
      sA += eA; sB += eB;
    }
    kA += cntA; kB += cntB;
  }
  float bgv = bg[l];
  float oA = accA / (sA + 1e-16f) + bgv;
  float oB = accB / (sB + 1e-16f) + bgv;
  float vA = silu_f(oA) + x2[(size_t)iA * D + l];
  float vB = silu_f(oB) + x2[(size_t)iB * D + l];
  if (FUSE) {
    // next layer's dual GEMM straight from LDS (xmid never materialized)
    xt[2 * w][l] = f2b(vA);
    xt[2 * w + 1][l] = f2b(vB);
    {
      ushort_t* xz = &xt[8][0];
      for (int e = threadIdx.x; e < 8 * 72; e += 256) xz[e] = 0;
    }
    __syncthreads();
    int t = w;
    int q = l >> 4, cn = l & 15;
    bf16x8 a0 = *(const bf16x8*)&xt[cn][q * 8];
    bf16x8 a1 = *(const bf16x8*)&xt[cn][q * 8 + 32];
#pragma unroll
    for (int m = 0; m < 2; ++m) {
      bf16x8 b0 = *(const bf16x8*)&wd[(size_t)((m * 8 + 0 * 4 + t) * 512 + l * 8)];
      bf16x8 b1 = *(const bf16x8*)&wd[(size_t)((m * 8 + 1 * 4 + t) * 512 + l * 8)];
      f32x4 z = {0.f, 0.f, 0.f, 0.f};
      f32x4 acc = __builtin_amdgcn_mfma_f32_16x16x32_bf16(a0, b0, z, 0, 0, 0);
      acc = __builtin_amdgcn_mfma_f32_16x16x32_bf16(a1, b1, acc, 0, 0, 0);
      if (q < 2) {
        float bb = (m == 1) ? b2[t * 16 + cn] : 0.f;
#pragma unroll
        for (int r = 0; r < 4; ++r) {
          size_t row = (size_t)base + q * 4 + r;
          if (m == 0)
            out1[row * D + t * 16 + cn] = f2b(acc[r]);
          else
            out2[row * D + t * 16 + cn] = acc[r] + bb;
        }
      }
    }
  } else {
    xout[(size_t)iA * D + l] = vA;
    xout[(size_t)iB * D + l] = vB;
  }
}

// ---------- launch ----------

extern "C" void kernel_launch(void* const* d_in, const int* in_sizes, int n_in,
                              void* d_out, int out_size, void* d_ws, size_t ws_size,
                              hipStream_t stream) {
  (void)in_sizes; (void)n_in; (void)out_size; (void)ws_size;
  const float* x  = (const float*)d_in[0];
  const int*   ei = (const int*)d_in[1];
  const float* ew = (const float*)d_in[2];
  const float* ea = (const float*)d_in[3];
  const float* P[2][12];
  for (int l = 0; l < 2; ++l)
    for (int j = 0; j < 12; ++j) P[l][j] = (const float*)d_in[4 + l * 12 + j];

  float* W = (float*)d_ws;
  const size_t o_rs    = 0;                          // NN+16 ints
  const size_t o_dinv  = o_rs + NN + 16;             // NN
  const size_t o_degs  = o_dinv + NN;                // NN
  const size_t o_wea   = o_degs + NN;                // 16 (wea2[8] used)
  const size_t o_scal  = o_wea + 16;                 // 1024
  const size_t o_bsum  = o_scal + 1024;              // 256
  const size_t o_hist  = o_bsum + 256;               // STOT ints
  const size_t o_recw  = o_hist + STOT;              // NE uint2
  const size_t o_reca  = o_recw + (size_t)NE * 2;    // NE uint
  const size_t o_rtmp  = o_reca + NE;                // NE uint2
  const size_t o_h16   = o_rtmp + (size_t)NE * 2;    // NN*D ushort
  const size_t o_xl16  = o_h16 + (size_t)NN * D / 2;
  const size_t o_res   = o_xl16 + (size_t)NN * D / 2;
  const size_t o_x2    = o_res + (size_t)NN * D;
  const size_t o_as    = o_x2 + (size_t)NN * D;      // NN*4
  const size_t o_ad    = o_as + (size_t)NN * 4;      // NN*4
  const size_t o_wg16  = o_ad + (size_t)NN * 4;      // 2*4096 ushort (16KB)
  const size_t o_wd16  = o_wg16 + 4096;              // 8192 ushort (16KB)

  int*      rs    = (int*)(W + o_rs);
  float*    dinv  = W + o_dinv;
  float*    degs  = W + o_degs;
  float*    wea2  = W + o_wea;
  float*    scal  = W + o_scal;
  int*      bsum  = (int*)(W + o_bsum);
  int*      histG = (int*)(W + o_hist);
  uint2*    recw  = (uint2*)(W + o_recw);
  uint_t*   reca  = (uint_t*)(W + o_reca);
  uint2*    rtmp  = (uint2*)(W + o_rtmp);
  ushort_t* h16   = (ushort_t*)(W + o_h16);
  ushort_t* xl16  = (ushort_t*)(W + o_xl16);
  float*    resb  = W + o_res;
  float*    x2b   = W + o_x2;
  float*    asb   = W + o_as;
  float*    adb   = W + o_ad;
  ushort_t* wg16  = (ushort_t*)(W + o_wg16);
  ushort_t* wd16  = (ushort_t*)(W + o_wd16);

  const int B = 256;
  const int gPre = NB1 + (NT + 3) / 4;  // hist blocks + layer0 gemm blocks
  const int gN2  = NN / 8;              // 8 nodes per block (4 waves x 2)

  k_pre<<<gPre, B, 0, stream>>>(ei, histG, x, P[0][0], P[0][2], P[0][3], h16, resb);
  k_scanA<<<SBLK + 1, B, 0, stream>>>(histG, bsum, scal,
                                      P[0][6], P[1][6], P[1][0], P[1][2],
                                      P[0][11], P[0][10], P[1][11], P[1][10],
                                      wg16, wd16, wea2, degs);
  k_scanC<<<SBLK, B, 0, stream>>>(histG, bsum);
  k_part<<<NB1, B, 0, stream>>>(ei, ew, ea, histG, rtmp, scal, degs);
  k_sfin<<<NBIN, B, 0, stream>>>(rtmp, histG, recw, reca, rs, dinv, degs, scal);

  // layer 0
  k_gcn_gat<<<gN2, B, 0, stream>>>(h16, resb, dinv, rs, recw,
                                   P[0][1], P[0][4], P[0][5],
                                   wg16, P[0][8], P[0][9],
                                   x2b, xl16, asb, adb);
  k_gat_fin<1><<<gN2, B, 0, stream>>>(xl16, x2b, asb, adb, rs, reca,
                                      wea2, scal, P[0][7],
                                      wd16, P[1][3], h16, resb, nullptr);
  // layer 1
  k_gcn_gat<<<gN2, B, 0, stream>>>(h16, resb, dinv, rs, recw,
                                   P[1][1], P[1][4], P[1][5],
                                   wg16 + 4096, P[1][8], P[1][9],
                                   x2b, xl16, asb, adb);
  k_gat_fin<0><<<gN2, B, 0, stream>>>(xl16, x2b, asb, adb, rs, reca,
                                      wea2 + 4, scal, P[1][7],
                                      nullptr, nullptr, nullptr, nullptr,
                                      (float*)d_out);
}

// Round 4
// 293.655 us; speedup vs baseline: 1.2089x; 1.2089x over previous
//
#include <hip/hip_runtime.h>
#include <hip/hip_fp16.h>

#define NN 50000
#define NE 800000
#define D 64
#define EPS 1e-5f
#define NT 3125   // NN/16 row-tiles for MFMA GEMMs
#define NB1 250   // partition blocks (NB1*EPB == NE)
#define EPB 3200  // edges per partition block
#define NBIN 196  // coarse bins = ceil(NN/256)
#define STOT 49152  // padded scan length (192*256 >= NBIN*NB1)
#define SBLK 192

typedef unsigned short ushort_t;
typedef unsigned int uint_t;
typedef __attribute__((ext_vector_type(8))) short bf16x8;
typedef __attribute__((ext_vector_type(4))) float f32x4;

__device__ __forceinline__ float wave_sum64(float v) {
#pragma unroll
  for (int m = 1; m <= 32; m <<= 1) v += __shfl_xor(v, m, 64);
  return v;
}
__device__ __forceinline__ int wave_sum64i(int v) {
#pragma unroll
  for (int m = 1; m <= 32; m <<= 1) v += __shfl_xor(v, m, 64);
  return v;
}
__device__ __forceinline__ float group_sum16(float v) {
#pragma unroll
  for (int m = 1; m <= 8; m <<= 1) v += __shfl_xor(v, m, 64);
  return v;
}
__device__ __forceinline__ float silu_f(float v) { return v / (1.f + __expf(-v)); }
__device__ __forceinline__ float lrelu_f(float v) { return v >= 0.f ? v : 0.2f * v; }
__device__ __forceinline__ ushort_t f2b(float x) {
  unsigned u = __float_as_uint(x);
  return (ushort_t)((u + 0x7FFFu + ((u >> 16) & 1u)) >> 16);
}
__device__ __forceinline__ float b2f(ushort_t u) {
  return __uint_as_float(((unsigned)u) << 16);
}
__device__ __forceinline__ ushort_t f2h(float x) {
  return __half_as_ushort(__float2half_rn(x));
}
__device__ __forceinline__ float h2f(unsigned u) {
  return __half2float(__ushort_as_half((ushort_t)(u & 0xFFFFu)));
}
__device__ __forceinline__ float sel4(float a, float b, float c, float d, int h) {
  float ab = (h & 1) ? b : a;
  float cd = (h & 1) ? d : c;
  return (h & 2) ? cd : ab;
}
__device__ __forceinline__ bf16x8 pack8(float4 a, float4 b) {
  bf16x8 r;
  r[0] = (short)f2b(a.x); r[1] = (short)f2b(a.y);
  r[2] = (short)f2b(a.z); r[3] = (short)f2b(a.w);
  r[4] = (short)f2b(b.x); r[5] = (short)f2b(b.y);
  r[6] = (short)f2b(b.z); r[7] = (short)f2b(b.w);
  return r;
}

// ---------- fused prep entry: hist (blocks 0..NB1-1) + layer0 dual GEMM ----------
__global__ void __launch_bounds__(256) k_pre(
    const int* __restrict__ ei, int* __restrict__ histG,
    const float* __restrict__ x, const float* __restrict__ W1,
    const float* __restrict__ W2, const float* __restrict__ b2,
    ushort_t* __restrict__ out1, float* __restrict__ out2) {
  __shared__ __align__(16) char smem[16384];
  if (blockIdx.x < NB1) {
    // coarse histogram role
    int* h = (int*)smem;
    int blk = blockIdx.x;
    for (int j = threadIdx.x; j < NBIN; j += 256) h[j] = 0;
    __syncthreads();
    int e0 = blk * EPB;
    for (int e = e0 + threadIdx.x; e < e0 + EPB; e += 256)
      atomicAdd(&h[ei[NE + e] >> 8], 1);
    __syncthreads();
    for (int j = threadIdx.x; j < NBIN; j += 256) histG[j * NB1 + blk] = h[j];
    return;
  }
  // layer-0 dual GEMM role (independent of prep)
  ushort_t* wf = (ushort_t*)smem;
  for (int e = threadIdx.x; e < 8192; e += 256) {
    int f = e >> 9, r = e & 511;
    int lane = r >> 3, j = r & 7;
    int m = f >> 3, s = (f >> 2) & 1, t = f & 3;
    int k = s * 32 + (lane >> 4) * 8 + j;
    int n = t * 16 + (lane & 15);
    const float* Wm = m ? W2 : W1;
    wf[e] = f2b(Wm[k * D + n]);
  }
  __syncthreads();
  int tile = (blockIdx.x - NB1) * 4 + (threadIdx.x >> 6);
  if (tile >= NT) return;
  int l = threadIdx.x & 63;
  int q = l >> 4, cn = l & 15;
  const float* xr = x + ((size_t)tile * 16 + cn) * D + q * 8;
  float4 xa = *(const float4*)xr;
  float4 xb = *(const float4*)(xr + 4);
  float4 xc = *(const float4*)(xr + 32);
  float4 xd = *(const float4*)(xr + 36);
  bf16x8 a0 = pack8(xa, xb), a1 = pack8(xc, xd);
  f32x4 acc1[4], acc2[4];
#pragma unroll
  for (int t = 0; t < 4; ++t) {
    bf16x8 b10 = *(const bf16x8*)&wf[(0 * 8 + 0 * 4 + t) * 512 + l * 8];
    bf16x8 b11 = *(const bf16x8*)&wf[(0 * 8 + 1 * 4 + t) * 512 + l * 8];
    bf16x8 b20 = *(const bf16x8*)&wf[(1 * 8 + 0 * 4 + t) * 512 + l * 8];
    bf16x8 b21 = *(const bf16x8*)&wf[(1 * 8 + 1 * 4 + t) * 512 + l * 8];
    f32x4 z = {0.f, 0.f, 0.f, 0.f};
    acc1[t] = __builtin_amdgcn_mfma_f32_16x16x32_bf16(a0, b10, z, 0, 0, 0);
    acc1[t] = __builtin_amdgcn_mfma_f32_16x16x32_bf16(a1, b11, acc1[t], 0, 0, 0);
    acc2[t] = __builtin_amdgcn_mfma_f32_16x16x32_bf16(a0, b20, z, 0, 0, 0);
    acc2[t] = __builtin_amdgcn_mfma_f32_16x16x32_bf16(a1, b21, acc2[t], 0, 0, 0);
  }
#pragma unroll
  for (int t = 0; t < 4; ++t) {
    float bb = b2[t * 16 + cn];
#pragma unroll
    for (int r = 0; r < 4; ++r) {
      size_t row = (size_t)tile * 16 + q * 4 + r;
      out1[row * D + t * 16 + cn] = f2b(acc1[t][r]);
      out2[row * D + t * 16 + cn] = acc2[t][r] + bb;
    }
  }
}

// ---------- scan A: block-local exclusive scan + block sums; block SBLK does
// one-time weight->fragment conversion, wea, scal zeroing ----------
__global__ void __launch_bounds__(256) k_scanA(
    int* __restrict__ histG, int* __restrict__ bsum, float* __restrict__ scal,
    const float* __restrict__ Wg0, const float* __restrict__ Wg1,
    const float* __restrict__ W11, const float* __restrict__ W21,
    const float* __restrict__ We0, const float* __restrict__ ae0,
    const float* __restrict__ We1, const float* __restrict__ ae1,
    ushort_t* __restrict__ wg16, ushort_t* __restrict__ wd16,
    float* __restrict__ wea2) {
  if (blockIdx.x == SBLK) {
    int tid = threadIdx.x;
    for (int t = tid; t < 1024; t += 256) scal[t] = 0.f;
    for (int e = tid; e < 4096; e += 256) {
      int f = e >> 9, r = e & 511;
      int lane = r >> 3, j = r & 7;
      int s = (f >> 2) & 1, t = f & 3;
      int k = s * 32 + (lane >> 4) * 8 + j;
      int n = t * 16 + (lane & 15);
      wg16[e] = f2b(Wg0[k * D + n]);
      wg16[4096 + e] = f2b(Wg1[k * D + n]);
    }
    for (int e = tid; e < 8192; e += 256) {
      int f = e >> 9, r = e & 511;
      int lane = r >> 3, j = r & 7;
      int m = f >> 3, s = (f >> 2) & 1, t = f & 3;
      int k = s * 32 + (lane >> 4) * 8 + j;
      int n = t * 16 + (lane & 15);
      const float* Wm = m ? W21 : W11;
      wd16[e] = f2b(Wm[k * D + n]);
    }
    if (tid < 64) {
      float v = group_sum16(We0[tid] * ae0[tid]);
      if ((tid & 15) == 0) wea2[tid >> 4] = v;
    } else if (tid < 128) {
      int c = tid - 64;
      float v = group_sum16(We1[c] * ae1[c]);
      if ((c & 15) == 0) wea2[4 + (c >> 4)] = v;
    }
    return;
  }
  __shared__ int sm[256];
  int j = threadIdx.x;
  int i = blockIdx.x * 256 + j;
  const int TOT = NBIN * NB1;
  int v = (i < TOT) ? histG[i] : 0;
  sm[j] = v;
  __syncthreads();
  for (int off = 1; off < 256; off <<= 1) {
    int t = (j >= off) ? sm[j - off] : 0;
    __syncthreads();
    sm[j] += t;
    __syncthreads();
  }
  if (i < TOT) histG[i] = sm[j] - v;  // block-local exclusive
  if (j == 255) bsum[blockIdx.x] = sm[255];
}

// ---------- scan C: each block derives its own prefix from raw bsum ----------
__global__ void __launch_bounds__(256) k_scanC(int* __restrict__ histG,
                                               const int* __restrict__ bsum) {
  __shared__ int ws4[4];
  int t = threadIdx.x;
  int v = (t < (int)blockIdx.x) ? bsum[t] : 0;
  v = wave_sum64i(v);
  if ((t & 63) == 0) ws4[t >> 6] = v;
  __syncthreads();
  int prefix = ws4[0] + ws4[1] + ws4[2] + ws4[3];
  int i = blockIdx.x * 256 + t;
  if (i < NBIN * NB1) histG[i] += prefix;
}

// Partition pass: scatter packed temp records into per-(bin,block) exclusive
// regions via LDS cursors (no global atomics). Also accumulates edge_attr sum.
__global__ void __launch_bounds__(256) k_part(
    const int* __restrict__ ei, const float* __restrict__ ew,
    const float* __restrict__ ea, const int* __restrict__ histG,
    uint2* __restrict__ rectmp, float* __restrict__ scal) {
  __shared__ int cur[NBIN];
  int blk = blockIdx.x;
  for (int j = threadIdx.x; j < NBIN; j += 256) cur[j] = histG[j * NB1 + blk];
  __syncthreads();
  int e0 = blk * EPB;
  float asum = 0.f;
  for (int e = e0 + threadIdx.x; e < e0 + EPB; e += 256) {
    int src = ei[e];
    int dst = ei[NE + e];
    float w = ew[e];
    float a = ea[e];
    asum += a;
    int slot = atomicAdd(&cur[dst >> 8], 1);
    uint2 r;
    r.x = (uint_t)(src & 0xFFFF) | ((uint_t)f2h(w) << 16);
    r.y = (uint_t)(dst & 0xFF) | ((uint_t)f2h(a) << 16);
    rectmp[slot] = r;
  }
  float s = wave_sum64(asum);
  if ((threadIdx.x & 63) == 0) {
    int slot = (blk * 4 + (threadIdx.x >> 6)) & 63;
    atomicAdd(&scal[(size_t)slot * 16], s);
  }
}

// Final counting sort within each coarse bucket: emits compact split records
// (recw = src|f16w, reca = src|f16ea) grouped by dst, rs[], and dinv[] via
// LDS per-dst weight-sum accumulation (no global atomics).
__global__ void __launch_bounds__(256) k_sfin(
    const uint2* __restrict__ rectmp, const int* __restrict__ histG,
    uint_t* __restrict__ recw, uint_t* __restrict__ reca, int* __restrict__ rs,
    float* __restrict__ dinv, float* __restrict__ scal) {
  __shared__ int cnt[256], sc[256], cur[256];
  __shared__ float wsum[256];
  int b = blockIdx.x;
  int t = threadIdx.x;
  int lo = histG[b * NB1];
  int hi = (b == NBIN - 1) ? NE : histG[(b + 1) * NB1];
  cnt[t] = 0;
  wsum[t] = 0.f;
  __syncthreads();
  for (int e = lo + t; e < hi; e += 256)
    atomicAdd(&cnt[rectmp[e].y & 0xFFu], 1);
  __syncthreads();
  int v = cnt[t];
  sc[t] = v;
  __syncthreads();
  for (int off = 1; off < 256; off <<= 1) {
    int u = (t >= off) ? sc[t - off] : 0;
    __syncthreads();
    sc[t] += u;
    __syncthreads();
  }
  int ex = sc[t] - v;  // exclusive within bucket
  int node = b * 256 + t;
  if (node < NN) rs[node] = lo + ex;
  if (b == NBIN - 1 && t == 0) rs[NN] = NE;
  cur[t] = lo + ex;
  __syncthreads();
  for (int e = lo + t; e < hi; e += 256) {
    uint2 r = rectmp[e];
    int dl = (int)(r.y & 0xFFu);
    int slot = atomicAdd(&cur[dl], 1);
    atomicAdd(&wsum[dl], h2f(r.x >> 16));
    uint_t src = r.x & 0xFFFFu;
    recw[slot] = r.x;                         // src | f16(w)<<16
    reca[slot] = src | (r.y & 0xFFFF0000u);   // src | f16(ea)<<16
  }
  __syncthreads();
  if (node < NN) dinv[node] = rsqrtf(1.f + wsum[t]);
  if (b == 0 && t == 0) {
    float s = 0.f;
    for (int j = 0; j < 64; ++j) s += scal[(size_t)j * 16];
    scal[1] = s / (float)NE;
  }
}

// ---------- fused GCN aggregate + LN + GAT node transform ----------
// 4 waves/block, 2 nodes/wave -> 8 nodes/block; MFMA tile rows 8..15 zeroed.
__global__ void __launch_bounds__(256) k_gcn_gat(
    const ushort_t* __restrict__ h16, const float* __restrict__ res,
    const float* __restrict__ dinv, const int* __restrict__ rs,
    const uint_t* __restrict__ recw,
    const float* __restrict__ gb, const float* __restrict__ lg,
    const float* __restrict__ lb,
    const ushort_t* __restrict__ wg, const float* __restrict__ att_src,
    const float* __restrict__ att_dst,
    float* __restrict__ x2, ushort_t* __restrict__ xl,
    float* __restrict__ a_s, float* __restrict__ a_d) {
  __shared__ int ss[4][64];
  __shared__ float swt[4][64];
  __shared__ __align__(16) ushort_t xt[16][72];  // 144B row stride
  int w = threadIdx.x >> 6;
  int l = threadIdx.x & 63;
  int base = blockIdx.x * 8;
  int iA = base + 2 * w;
  int iB = iA + 1;
  int half = l >> 5, cp = l & 31;
  float diA = dinv[iA], diB = dinv[iB];
  float accA = diA * diA * b2f(h16[(size_t)iA * D + l]);
  float accB = diB * diB * b2f(h16[(size_t)iB * D + l]);
  int kA = rs[iA], kA1 = rs[iA + 1];
  int kB = rs[iB], kB1 = rs[iB + 1];
  while (kA < kA1 || kB < kB1) {
    int cntA = min(32, kA1 - kA);
    int cntB = min(32, kB1 - kB);
    int src = 0; float wn = 0.f;
    if (half == 0) {
      if (cp < cntA) {
        uint_t r = recw[(size_t)(kA + cp)];
        src = (int)(r & 0xFFFFu);
        wn = dinv[src] * h2f(r >> 16) * diA;
      }
    } else {
      if (cp < cntB) {
        uint_t r = recw[(size_t)(kB + cp)];
        src = (int)(r & 0xFFFFu);
        wn = dinv[src] * h2f(r >> 16) * diB;
      }
    }
    ss[w][l] = src;
    swt[w][l] = wn;
    int nm = max(cntA, cntB);
    int j = 0;
    for (; j + 4 <= nm; j += 4) {
      int4 sa = *(const int4*)&ss[w][j];
      int4 sb = *(const int4*)&ss[w][32 + j];
      float4 wa = *(const float4*)&swt[w][j];
      float4 wb = *(const float4*)&swt[w][32 + j];
      float a0 = b2f(h16[(size_t)sa.x * D + l]);
      float b0 = b2f(h16[(size_t)sb.x * D + l]);
      float a1 = b2f(h16[(size_t)sa.y * D + l]);
      float b1 = b2f(h16[(size_t)sb.y * D + l]);
      float a2 = b2f(h16[(size_t)sa.z * D + l]);
      float b2v = b2f(h16[(size_t)sb.z * D + l]);
      float a3 = b2f(h16[(size_t)sa.w * D + l]);
      float b3 = b2f(h16[(size_t)sb.w * D + l]);
      accA = fmaf(wa.x, a0, accA); accB = fmaf(wb.x, b0, accB);
      accA = fmaf(wa.y, a1, accA); accB = fmaf(wb.y, b1, accB);
      accA = fmaf(wa.z, a2, accA); accB = fmaf(wb.z, b2v, accB);
      accA = fmaf(wa.w, a3, accA); accB = fmaf(wb.w, b3, accB);
    }
    for (; j < nm; ++j) {
      int sA = ss[w][j], sB = ss[w][32 + j];
      float wA = swt[w][j], wB = swt[w][32 + j];
      float vA = b2f(h16[(size_t)sA * D + l]);
      float vB = b2f(h16[(size_t)sB * D + l]);
      accA = fmaf(wA, vA, accA);
      accB = fmaf(wB, vB, accB);
    }
    kA += cntA; kB += cntB;
  }
  float gbv = gb[l], lgv = lg[l], lbv = lb[l];
  float x1A = silu_f(accA + gbv) + res[(size_t)iA * D + l];
  float x1B = silu_f(accB + gbv) + res[(size_t)iB * D + l];
  float muA = wave_sum64(x1A) * (1.f / 64.f);
  float muB = wave_sum64(x1B) * (1.f / 64.f);
  float dA = x1A - muA, dB = x1B - muB;
  float varA = wave_sum64(dA * dA) * (1.f / 64.f);
  float varB = wave_sum64(dB * dB) * (1.f / 64.f);
  float oA = dA * rsqrtf(varA + EPS) * lgv + lbv;
  float oB = dB * rsqrtf(varB + EPS) * lgv + lbv;
  x2[(size_t)iA * D + l] = oA;
  x2[(size_t)iB * D + l] = oB;
  xt[2 * w][l] = f2b(oA);
  xt[2 * w + 1][l] = f2b(oB);
  {
    ushort_t* xz = &xt[8][0];
    for (int e = threadIdx.x; e < 8 * 72; e += 256) xz[e] = 0;
  }
  __syncthreads();
  // GAT node transform: xl = bf16(x2) @ Wg (wave w owns col-tile t=w)
  int t = w;
  int q = l >> 4, cn = l & 15;
  bf16x8 a0 = *(const bf16x8*)&xt[cn][q * 8];
  bf16x8 a1 = *(const bf16x8*)&xt[cn][q * 8 + 32];
  bf16x8 b0 = *(const bf16x8*)&wg[(size_t)((0 * 4 + t) * 512 + l * 8)];
  bf16x8 b1 = *(const bf16x8*)&wg[(size_t)((1 * 4 + t) * 512 + l * 8)];
  f32x4 z = {0.f, 0.f, 0.f, 0.f};
  f32x4 acc = __builtin_amdgcn_mfma_f32_16x16x32_bf16(a0, b0, z, 0, 0, 0);
  acc = __builtin_amdgcn_mfma_f32_16x16x32_bf16(a1, b1, acc, 0, 0, 0);
  if (q < 2) {  // only rows 0..7 are real nodes
    float av = att_src[t * 16 + cn];
    float dv = att_dst[t * 16 + cn];
#pragma unroll
    for (int r = 0; r < 4; ++r) {
      size_t row = (size_t)base + q * 4 + r;
      xl[row * D + t * 16 + cn] = f2b(acc[r]);
      float vs = group_sum16(acc[r] * av);
      float vd = group_sum16(acc[r] * dv);
      if (cn == 0) {
        a_s[row * 4 + t] = vs;
        a_d[row * 4 + t] = vd;
      }
    }
  }
}

// ---------- fused GAT aggregate (+ optional next-layer dual GEMM) ----------
template <int FUSE>
__global__ void __launch_bounds__(256) k_gat_fin(
    const ushort_t* __restrict__ xl16, const float* __restrict__ x2,
    const float* __restrict__ a_s, const float* __restrict__ a_d,
    const int* __restrict__ rs, const uint_t* __restrict__ reca,
    const float* __restrict__ wea, const float* __restrict__ scal,
    const float* __restrict__ bg,
    const ushort_t* __restrict__ wd, const float* __restrict__ b2,
    ushort_t* __restrict__ out1, float* __restrict__ out2,
    float* __restrict__ xout) {
  __shared__ int ss[4][64];
  __shared__ float el[4][4][68];
  __shared__ __align__(16) ushort_t xt[16][72];
  int w = threadIdx.x >> 6;
  int base = blockIdx.x * 8;
  int iA = base + 2 * w;
  int iB = iA + 1;
  int l = threadIdx.x & 63;
  int half = l >> 5, cp = l & 31;
  int hh = l >> 4;
  float4 wv4 = *(const float4*)wea;
  float mean_attr = scal[1];
  float we_h = sel4(wv4.x, wv4.y, wv4.z, wv4.w, hh);
  float ad_hA = a_d[(size_t)iA * 4 + hh], as_iA = a_s[(size_t)iA * 4 + hh];
  float ad_hB = a_d[(size_t)iB * 4 + hh], as_iB = a_s[(size_t)iB * 4 + hh];
  float eSA = __expf(lrelu_f(as_iA + ad_hA + mean_attr * we_h));
  float eSB = __expf(lrelu_f(as_iB + ad_hB + mean_attr * we_h));
  float sA = eSA, sB = eSB;
  float accA = eSA * b2f(xl16[(size_t)iA * D + l]);
  float accB = eSB * b2f(xl16[(size_t)iB * D + l]);
  const float* adp = a_d + (size_t)(half ? iB : iA) * 4;
  float4 ad4 = *(const float4*)adp;
  int kA = rs[iA], kA1 = rs[iA + 1];
  int kB = rs[iB], kB1 = rs[iB + 1];
  while (kA < kA1 || kB < kB1) {
    int cntA = min(32, kA1 - kA);
    int cntB = min(32, kB1 - kB);
    int myk = half ? kB : kA;
    int mycnt = half ? cntB : cntA;
    int src = 0;
    float e0v = 0.f, e1v = 0.f, e2v = 0.f, e3v = 0.f;
    if (cp < mycnt) {
      uint_t r = reca[(size_t)(myk + cp)];
      src = (int)(r & 0xFFFFu);
      float ea = h2f(r >> 16);
      float4 as4 = *(const float4*)(a_s + (size_t)src * 4);
      e0v = __expf(lrelu_f(as4.x + fmaf(ea, wv4.x, ad4.x)));
      e1v = __expf(lrelu_f(as4.y + fmaf(ea, wv4.y, ad4.y)));
      e2v = __expf(lrelu_f(as4.z + fmaf(ea, wv4.z, ad4.z)));
      e3v = __expf(lrelu_f(as4.w + fmaf(ea, wv4.w, ad4.w)));
    }
    ss[w][l] = src;
    el[w][0][l] = e0v;
    el[w][1][l] = e1v;
    el[w][2][l] = e2v;
    el[w][3][l] = e3v;
    int nm = max(cntA, cntB);
    int j = 0;
    for (; j + 4 <= nm; j += 4) {
      int4 sa = *(const int4*)&ss[w][j];
      int4 sb = *(const int4*)&ss[w][32 + j];
      float4 ea4 = *(const float4*)&el[w][hh][j];
      float4 eb4 = *(const float4*)&el[w][hh][32 + j];
      float a0 = b2f(xl16[(size_t)sa.x * D + l]);
      float b0 = b2f(xl16[(size_t)sb.x * D + l]);
      float a1 = b2f(xl16[(size_t)sa.y * D + l]);
      float b1 = b2f(xl16[(size_t)sb.y * D + l]);
      float a2 = b2f(xl16[(size_t)sa.z * D + l]);
      float b2v = b2f(xl16[(size_t)sb.z * D + l]);
      float a3 = b2f(xl16[(size_t)sa.w * D + l]);
      float b3 = b2f(xl16[(size_t)sb.w * D + l]);
      accA = fmaf(ea4.x, a0, accA); accB = fmaf(eb4.x, b0, accB);
      accA = fmaf(ea4.y, a1, accA); accB = fmaf(eb4.y, b1, accB);
      accA = fmaf(ea4.z, a2, accA); accB = fmaf(eb4.z, b2v, accB);
      accA = fmaf(ea4.w, a3, accA); accB = fmaf(eb4.w, b3, accB);
      sA += (ea4.x + ea4.y) + (ea4.z + ea4.w);
      sB += (eb4.x + eb4.y) + (eb4.z + eb4.w);
    }
    for (; j < nm; ++j) {
      int srcA = ss[w][j], srcB = ss[w][32 + j];
      float eA = el[w][hh][j], eB = el[w][hh][32 + j];
      float vA = b2f(xl16[(size_t)srcA * D + l]);
      float vB = b2f(xl16[(size_t)srcB * D + l]);
      accA = fmaf(eA, vA, accA);
      accB = fmaf(eB, vB, accB);
      sA += eA; sB += eB;
    }
    kA += cntA; kB += cntB;
  }
  float bgv = bg[l];
  float oA = accA / (sA + 1e-16f) + bgv;
  float oB = accB / (sB + 1e-16f) + bgv;
  float vA = silu_f(oA) + x2[(size_t)iA * D + l];
  float vB = silu_f(oB) + x2[(size_t)iB * D + l];
  if (FUSE) {
    // next layer's dual GEMM straight from LDS (xmid never materialized)
    xt[2 * w][l] = f2b(vA);
    xt[2 * w + 1][l] = f2b(vB);
    {
      ushort_t* xz = &xt[8][0];
      for (int e = threadIdx.x; e < 8 * 72; e += 256) xz[e] = 0;
    }
    __syncthreads();
    int t = w;
    int q = l >> 4, cn = l & 15;
    bf16x8 a0 = *(const bf16x8*)&xt[cn][q * 8];
    bf16x8 a1 = *(const bf16x8*)&xt[cn][q * 8 + 32];
#pragma unroll
    for (int m = 0; m < 2; ++m) {
      bf16x8 b0 = *(const bf16x8*)&wd[(size_t)((m * 8 + 0 * 4 + t) * 512 + l * 8)];
      bf16x8 b1 = *(const bf16x8*)&wd[(size_t)((m * 8 + 1 * 4 + t) * 512 + l * 8)];
      f32x4 z = {0.f, 0.f, 0.f, 0.f};
      f32x4 acc = __builtin_amdgcn_mfma_f32_16x16x32_bf16(a0, b0, z, 0, 0, 0);
      acc = __builtin_amdgcn_mfma_f32_16x16x32_bf16(a1, b1, acc, 0, 0, 0);
      if (q < 2) {
        float bb = (m == 1) ? b2[t * 16 + cn] : 0.f;
#pragma unroll
        for (int r = 0; r < 4; ++r) {
          size_t row = (size_t)base + q * 4 + r;
          if (m == 0)
            out1[row * D + t * 16 + cn] = f2b(acc[r]);
          else
            out2[row * D + t * 16 + cn] = acc[r] + bb;
        }
      }
    }
  } else {
    xout[(size_t)iA * D + l] = vA;
    xout[(size_t)iB * D + l] = vB;
  }
}

// ---------- launch ----------

extern "C" void kernel_launch(void* const* d_in, const int* in_sizes, int n_in,
                              void* d_out, int out_size, void* d_ws, size_t ws_size,
                              hipStream_t stream) {
  (void)in_sizes; (void)n_in; (void)out_size; (void)ws_size;
  const float* x  = (const float*)d_in[0];
  const int*   ei = (const int*)d_in[1];
  const float* ew = (const float*)d_in[2];
  const float* ea = (const float*)d_in[3];
  const float* P[2][12];
  for (int l = 0; l < 2; ++l)
    for (int j = 0; j < 12; ++j) P[l][j] = (const float*)d_in[4 + l * 12 + j];

  float* W = (float*)d_ws;
  const size_t o_rs    = 0;                          // NN+16 ints
  const size_t o_dinv  = o_rs + NN + 16;             // NN
  const size_t o_wea   = o_dinv + NN;                // 16 (wea2[8] used)
  const size_t o_scal  = o_wea + 16;                 // 1024
  const size_t o_bsum  = o_scal + 1024;              // 256
  const size_t o_hist  = o_bsum + 256;               // STOT ints
  const size_t o_recw  = o_hist + STOT;              // NE uint
  const size_t o_reca  = o_recw + NE;                // NE uint
  const size_t o_rtmp  = o_reca + NE;                // NE uint2
  const size_t o_h16   = o_rtmp + (size_t)NE * 2;    // NN*D ushort
  const size_t o_xl16  = o_h16 + (size_t)NN * D / 2;
  const size_t o_res   = o_xl16 + (size_t)NN * D / 2;
  const size_t o_x2    = o_res + (size_t)NN * D;
  const size_t o_as    = o_x2 + (size_t)NN * D;      // NN*4
  const size_t o_ad    = o_as + (size_t)NN * 4;      // NN*4
  const size_t o_wg16  = o_ad + (size_t)NN * 4;      // 2*4096 ushort (16KB)
  const size_t o_wd16  = o_wg16 + 4096;              // 8192 ushort (16KB)

  int*      rs    = (int*)(W + o_rs);
  float*    dinv  = W + o_dinv;
  float*    wea2  = W + o_wea;
  float*    scal  = W + o_scal;
  int*      bsum  = (int*)(W + o_bsum);
  int*      histG = (int*)(W + o_hist);
  uint_t*   recw  = (uint_t*)(W + o_recw);
  uint_t*   reca  = (uint_t*)(W + o_reca);
  uint2*    rtmp  = (uint2*)(W + o_rtmp);
  ushort_t* h16   = (ushort_t*)(W + o_h16);
  ushort_t* xl16  = (ushort_t*)(W + o_xl16);
  float*    resb  = W + o_res;
  float*    x2b   = W + o_x2;
  float*    asb   = W + o_as;
  float*    adb   = W + o_ad;
  ushort_t* wg16  = (ushort_t*)(W + o_wg16);
  ushort_t* wd16  = (ushort_t*)(W + o_wd16);

  const int B = 256;
  const int gPre = NB1 + (NT + 3) / 4;  // hist blocks + layer0 gemm blocks
  const int gN2  = NN / 8;              // 8 nodes per block (4 waves x 2)

  k_pre<<<gPre, B, 0, stream>>>(ei, histG, x, P[0][0], P[0][2], P[0][3], h16, resb);
  k_scanA<<<SBLK + 1, B, 0, stream>>>(histG, bsum, scal,
                                      P[0][6], P[1][6], P[1][0], P[1][2],
                                      P[0][11], P[0][10], P[1][11], P[1][10],
                                      wg16, wd16, wea2);
  k_scanC<<<SBLK, B, 0, stream>>>(histG, bsum);
  k_part<<<NB1, B, 0, stream>>>(ei, ew, ea, histG, rtmp, scal);
  k_sfin<<<NBIN, B, 0, stream>>>(rtmp, histG, recw, reca, rs, dinv, scal);

  // layer 0
  k_gcn_gat<<<gN2, B, 0, stream>>>(h16, resb, dinv, rs, recw,
                                   P[0][1], P[0][4], P[0][5],
                                   wg16, P[0][8], P[0][9],
                                   x2b, xl16, asb, adb);
  k_gat_fin<1><<<gN2, B, 0, stream>>>(xl16, x2b, asb, adb, rs, reca,
                                      wea2, scal, P[0][7],
                                      wd16, P[1][3], h16, resb, nullptr);
  // layer 1
  k_gcn_gat<<<gN2, B, 0, stream>>>(h16, resb, dinv, rs, recw,
                                   P[1][1], P[1][4], P[1][5],
                                   wg16 + 4096, P[1][8], P[1][9],
                                   x2b, xl16, asb, adb);
  k_gat_fin<0><<<gN2, B, 0, stream>>>(xl16, x2b, asb, adb, rs, reca,
                                      wea2 + 4, scal, P[1][7],
                                      nullptr, nullptr, nullptr, nullptr,
                                      (float*)d_out);
}

// Round 5
// 285.477 us; speedup vs baseline: 1.2435x; 1.0286x over previous
//
#include <hip/hip_runtime.h>
#include <hip/hip_fp16.h>

#define NN 50000
#define NE 800000
#define D 64
#define EPS 1e-5f
#define NT 3125   // NN/16 row-tiles for MFMA GEMMs
#define NB1 250   // partition blocks (NB1*EPB == NE)
#define EPB 3200  // edges per partition block
#define NBIN 196  // coarse bins = ceil(NN/256)
#define STOT 49152  // padded scan length (192*256 >= NBIN*NB1)
#define SBLK 192

typedef unsigned short ushort_t;
typedef unsigned int uint_t;
typedef __attribute__((ext_vector_type(8))) short bf16x8;
typedef __attribute__((ext_vector_type(4))) float f32x4;

__device__ __forceinline__ float wave_sum64(float v) {
#pragma unroll
  for (int m = 1; m <= 32; m <<= 1) v += __shfl_xor(v, m, 64);
  return v;
}
__device__ __forceinline__ float half_sum32(float v) {
#pragma unroll
  for (int m = 1; m <= 16; m <<= 1) v += __shfl_xor(v, m, 64);
  return v;
}
__device__ __forceinline__ int wave_sum64i(int v) {
#pragma unroll
  for (int m = 1; m <= 32; m <<= 1) v += __shfl_xor(v, m, 64);
  return v;
}
__device__ __forceinline__ float group_sum16(float v) {
#pragma unroll
  for (int m = 1; m <= 8; m <<= 1) v += __shfl_xor(v, m, 64);
  return v;
}
__device__ __forceinline__ float silu_f(float v) { return v / (1.f + __expf(-v)); }
__device__ __forceinline__ float lrelu_f(float v) { return v >= 0.f ? v : 0.2f * v; }
__device__ __forceinline__ ushort_t f2b(float x) {
  unsigned u = __float_as_uint(x);
  return (ushort_t)((u + 0x7FFFu + ((u >> 16) & 1u)) >> 16);
}
__device__ __forceinline__ float b2f(ushort_t u) {
  return __uint_as_float(((unsigned)u) << 16);
}
__device__ __forceinline__ float b2f_lo(uint_t u) {
  return __uint_as_float(u << 16);
}
__device__ __forceinline__ float b2f_hi(uint_t u) {
  return __uint_as_float(u & 0xFFFF0000u);
}
__device__ __forceinline__ ushort_t f2h(float x) {
  return __half_as_ushort(__float2half_rn(x));
}
__device__ __forceinline__ float h2f(unsigned u) {
  return __half2float(__ushort_as_half((ushort_t)(u & 0xFFFFu)));
}
__device__ __forceinline__ float sel4(float a, float b, float c, float d, int h) {
  float ab = (h & 1) ? b : a;
  float cd = (h & 1) ? d : c;
  return (h & 2) ? cd : ab;
}
__device__ __forceinline__ bf16x8 pack8(float4 a, float4 b) {
  bf16x8 r;
  r[0] = (short)f2b(a.x); r[1] = (short)f2b(a.y);
  r[2] = (short)f2b(a.z); r[3] = (short)f2b(a.w);
  r[4] = (short)f2b(b.x); r[5] = (short)f2b(b.y);
  r[6] = (short)f2b(b.z); r[7] = (short)f2b(b.w);
  return r;
}

// ---------- fused prep entry: hist (blocks 0..NB1-1) + layer0 dual GEMM ----------
__global__ void __launch_bounds__(256) k_pre(
    const int* __restrict__ ei, int* __restrict__ histG,
    const float* __restrict__ x, const float* __restrict__ W1,
    const float* __restrict__ W2, const float* __restrict__ b2,
    ushort_t* __restrict__ out1, float* __restrict__ out2) {
  __shared__ __align__(16) char smem[16384];
  if (blockIdx.x < NB1) {
    // coarse histogram role
    int* h = (int*)smem;
    int blk = blockIdx.x;
    for (int j = threadIdx.x; j < NBIN; j += 256) h[j] = 0;
    __syncthreads();
    int e0 = blk * EPB;
    for (int e = e0 + threadIdx.x; e < e0 + EPB; e += 256)
      atomicAdd(&h[ei[NE + e] >> 8], 1);
    __syncthreads();
    for (int j = threadIdx.x; j < NBIN; j += 256) histG[j * NB1 + blk] = h[j];
    return;
  }
  // layer-0 dual GEMM role (independent of prep)
  ushort_t* wf = (ushort_t*)smem;
  for (int e = threadIdx.x; e < 8192; e += 256) {
    int f = e >> 9, r = e & 511;
    int lane = r >> 3, j = r & 7;
    int m = f >> 3, s = (f >> 2) & 1, t = f & 3;
    int k = s * 32 + (lane >> 4) * 8 + j;
    int n = t * 16 + (lane & 15);
    const float* Wm = m ? W2 : W1;
    wf[e] = f2b(Wm[k * D + n]);
  }
  __syncthreads();
  int tile = (blockIdx.x - NB1) * 4 + (threadIdx.x >> 6);
  if (tile >= NT) return;
  int l = threadIdx.x & 63;
  int q = l >> 4, cn = l & 15;
  const float* xr = x + ((size_t)tile * 16 + cn) * D + q * 8;
  float4 xa = *(const float4*)xr;
  float4 xb = *(const float4*)(xr + 4);
  float4 xc = *(const float4*)(xr + 32);
  float4 xd = *(const float4*)(xr + 36);
  bf16x8 a0 = pack8(xa, xb), a1 = pack8(xc, xd);
  f32x4 acc1[4], acc2[4];
#pragma unroll
  for (int t = 0; t < 4; ++t) {
    bf16x8 b10 = *(const bf16x8*)&wf[(0 * 8 + 0 * 4 + t) * 512 + l * 8];
    bf16x8 b11 = *(const bf16x8*)&wf[(0 * 8 + 1 * 4 + t) * 512 + l * 8];
    bf16x8 b20 = *(const bf16x8*)&wf[(1 * 8 + 0 * 4 + t) * 512 + l * 8];
    bf16x8 b21 = *(const bf16x8*)&wf[(1 * 8 + 1 * 4 + t) * 512 + l * 8];
    f32x4 z = {0.f, 0.f, 0.f, 0.f};
    acc1[t] = __builtin_amdgcn_mfma_f32_16x16x32_bf16(a0, b10, z, 0, 0, 0);
    acc1[t] = __builtin_amdgcn_mfma_f32_16x16x32_bf16(a1, b11, acc1[t], 0, 0, 0);
    acc2[t] = __builtin_amdgcn_mfma_f32_16x16x32_bf16(a0, b20, z, 0, 0, 0);
    acc2[t] = __builtin_amdgcn_mfma_f32_16x16x32_bf16(a1, b21, acc2[t], 0, 0, 0);
  }
#pragma unroll
  for (int t = 0; t < 4; ++t) {
    float bb = b2[t * 16 + cn];
#pragma unroll
    for (int r = 0; r < 4; ++r) {
      size_t row = (size_t)tile * 16 + q * 4 + r;
      out1[row * D + t * 16 + cn] = f2b(acc1[t][r]);
      out2[row * D + t * 16 + cn] = acc2[t][r] + bb;
    }
  }
}

// ---------- scan A: block-local exclusive scan + block sums; block SBLK does
// one-time weight->fragment conversion, wea, scal zeroing ----------
__global__ void __launch_bounds__(256) k_scanA(
    int* __restrict__ histG, int* __restrict__ bsum, float* __restrict__ scal,
    const float* __restrict__ Wg0, const float* __restrict__ Wg1,
    const float* __restrict__ W11, const float* __restrict__ W21,
    const float* __restrict__ We0, const float* __restrict__ ae0,
    const float* __restrict__ We1, const float* __restrict__ ae1,
    ushort_t* __restrict__ wg16, ushort_t* __restrict__ wd16,
    float* __restrict__ wea2) {
  if (blockIdx.x == SBLK) {
    int tid = threadIdx.x;
    for (int t = tid; t < 1024; t += 256) scal[t] = 0.f;
    for (int e = tid; e < 4096; e += 256) {
      int f = e >> 9, r = e & 511;
      int lane = r >> 3, j = r & 7;
      int s = (f >> 2) & 1, t = f & 3;
      int k = s * 32 + (lane >> 4) * 8 + j;
      int n = t * 16 + (lane & 15);
      wg16[e] = f2b(Wg0[k * D + n]);
      wg16[4096 + e] = f2b(Wg1[k * D + n]);
    }
    for (int e = tid; e < 8192; e += 256) {
      int f = e >> 9, r = e & 511;
      int lane = r >> 3, j = r & 7;
      int m = f >> 3, s = (f >> 2) & 1, t = f & 3;
      int k = s * 32 + (lane >> 4) * 8 + j;
      int n = t * 16 + (lane & 15);
      const float* Wm = m ? W21 : W11;
      wd16[e] = f2b(Wm[k * D + n]);
    }
    if (tid < 64) {
      float v = group_sum16(We0[tid] * ae0[tid]);
      if ((tid & 15) == 0) wea2[tid >> 4] = v;
    } else if (tid < 128) {
      int c = tid - 64;
      float v = group_sum16(We1[c] * ae1[c]);
      if ((c & 15) == 0) wea2[4 + (c >> 4)] = v;
    }
    return;
  }
  __shared__ int sm[256];
  int j = threadIdx.x;
  int i = blockIdx.x * 256 + j;
  const int TOT = NBIN * NB1;
  int v = (i < TOT) ? histG[i] : 0;
  sm[j] = v;
  __syncthreads();
  for (int off = 1; off < 256; off <<= 1) {
    int t = (j >= off) ? sm[j - off] : 0;
    __syncthreads();
    sm[j] += t;
    __syncthreads();
  }
  if (i < TOT) histG[i] = sm[j] - v;  // block-local exclusive
  if (j == 255) bsum[blockIdx.x] = sm[255];
}

// ---------- scan C: each block derives its own prefix from raw bsum ----------
__global__ void __launch_bounds__(256) k_scanC(int* __restrict__ histG,
                                               const int* __restrict__ bsum) {
  __shared__ int ws4[4];
  int t = threadIdx.x;
  int v = (t < (int)blockIdx.x) ? bsum[t] : 0;
  v = wave_sum64i(v);
  if ((t & 63) == 0) ws4[t >> 6] = v;
  __syncthreads();
  int prefix = ws4[0] + ws4[1] + ws4[2] + ws4[3];
  int i = blockIdx.x * 256 + t;
  if (i < NBIN * NB1) histG[i] += prefix;
}

// Partition pass: scatter packed temp records into per-(bin,block) exclusive
// regions via LDS cursors (no global atomics). Also accumulates edge_attr sum.
__global__ void __launch_bounds__(256) k_part(
    const int* __restrict__ ei, const float* __restrict__ ew,
    const float* __restrict__ ea, const int* __restrict__ histG,
    uint2* __restrict__ rectmp, float* __restrict__ scal) {
  __shared__ int cur[NBIN];
  int blk = blockIdx.x;
  for (int j = threadIdx.x; j < NBIN; j += 256) cur[j] = histG[j * NB1 + blk];
  __syncthreads();
  int e0 = blk * EPB;
  float asum = 0.f;
  for (int e = e0 + threadIdx.x; e < e0 + EPB; e += 256) {
    int src = ei[e];
    int dst = ei[NE + e];
    float w = ew[e];
    float a = ea[e];
    asum += a;
    int slot = atomicAdd(&cur[dst >> 8], 1);
    uint2 r;
    r.x = (uint_t)(src & 0xFFFF) | ((uint_t)f2h(w) << 16);
    r.y = (uint_t)(dst & 0xFF) | ((uint_t)f2h(a) << 16);
    rectmp[slot] = r;
  }
  float s = wave_sum64(asum);
  if ((threadIdx.x & 63) == 0) {
    int slot = (blk * 4 + (threadIdx.x >> 6)) & 63;
    atomicAdd(&scal[(size_t)slot * 16], s);
  }
}

// Final counting sort within each coarse bucket: emits compact split records
// (recw = src|f16w, reca = src|f16ea) grouped by dst, rs[], and dinv[] via
// LDS per-dst weight-sum accumulation (no global atomics).
__global__ void __launch_bounds__(256) k_sfin(
    const uint2* __restrict__ rectmp, const int* __restrict__ histG,
    uint_t* __restrict__ recw, uint_t* __restrict__ reca, int* __restrict__ rs,
    float* __restrict__ dinv, float* __restrict__ scal) {
  __shared__ int cnt[256], sc[256], cur[256];
  __shared__ float wsum[256];
  int b = blockIdx.x;
  int t = threadIdx.x;
  int lo = histG[b * NB1];
  int hi = (b == NBIN - 1) ? NE : histG[(b + 1) * NB1];
  cnt[t] = 0;
  wsum[t] = 0.f;
  __syncthreads();
  for (int e = lo + t; e < hi; e += 256)
    atomicAdd(&cnt[rectmp[e].y & 0xFFu], 1);
  __syncthreads();
  int v = cnt[t];
  sc[t] = v;
  __syncthreads();
  for (int off = 1; off < 256; off <<= 1) {
    int u = (t >= off) ? sc[t - off] : 0;
    __syncthreads();
    sc[t] += u;
    __syncthreads();
  }
  int ex = sc[t] - v;  // exclusive within bucket
  int node = b * 256 + t;
  if (node < NN) rs[node] = lo + ex;
  if (b == NBIN - 1 && t == 0) rs[NN] = NE;
  cur[t] = lo + ex;
  __syncthreads();
  for (int e = lo + t; e < hi; e += 256) {
    uint2 r = rectmp[e];
    int dl = (int)(r.y & 0xFFu);
    int slot = atomicAdd(&cur[dl], 1);
    atomicAdd(&wsum[dl], h2f(r.x >> 16));
    uint_t src = r.x & 0xFFFFu;
    recw[slot] = r.x;                         // src | f16(w)<<16
    reca[slot] = src | (r.y & 0xFFFF0000u);   // src | f16(ea)<<16
  }
  __syncthreads();
  if (node < NN) dinv[node] = rsqrtf(1.f + wsum[t]);
  if (b == 0 && t == 0) {
    float s = 0.f;
    for (int j = 0; j < 64; ++j) s += scal[(size_t)j * 16];
    scal[1] = s / (float)NE;
  }
}

// ---------- fused GCN aggregate + LN + GAT node transform ----------
// 4 waves/block, 2 nodes/wave (half-wave per node, 2 cols/lane).
__global__ void __launch_bounds__(256) k_gcn_gat(
    const ushort_t* __restrict__ h16, const float* __restrict__ res,
    const float* __restrict__ dinv, const int* __restrict__ rs,
    const uint_t* __restrict__ recw,
    const float* __restrict__ gb, const float* __restrict__ lg,
    const float* __restrict__ lb,
    const ushort_t* __restrict__ wg, const float* __restrict__ att_src,
    const float* __restrict__ att_dst,
    float* __restrict__ x2, ushort_t* __restrict__ xl,
    float* __restrict__ a_s, float* __restrict__ a_d) {
  __shared__ int ss[4][64];
  __shared__ float swt[4][64];
  __shared__ __align__(16) ushort_t xt[16][72];  // 144B row stride
  int w = threadIdx.x >> 6;
  int l = threadIdx.x & 63;
  int base = blockIdx.x * 8;
  int half = l >> 5, c = l & 31;   // half: 0=node A, 1=node B; cols 2c,2c+1
  int iA = base + 2 * w;
  int iB = iA + 1;
  int i = iA + half;
  float di = dinv[i];
  uint_t u0 = *(const uint_t*)&h16[(size_t)i * D + 2 * c];
  float dii = di * di;
  float acc0 = dii * b2f_lo(u0);
  float acc1 = dii * b2f_hi(u0);
  int kA = rs[iA], kA1 = rs[iA + 1];
  int kB = rs[iB], kB1 = rs[iB + 1];
  int sbase = half * 32;
  while (kA < kA1 || kB < kB1) {
    int cntA = min(32, kA1 - kA);
    int cntB = min(32, kB1 - kB);
    int myk = half ? kB : kA;
    int mycnt = half ? cntB : cntA;
    int src = 0; float wn = 0.f;
    if (c < mycnt) {
      uint_t r = recw[(size_t)(myk + c)];
      src = (int)(r & 0xFFFFu);
      wn = dinv[src] * h2f(r >> 16) * di;
    }
    ss[w][l] = src;
    swt[w][l] = wn;
    int nm = max(cntA, cntB);
    int j = 0;
    for (; j + 4 <= nm; j += 4) {
      int4 s4 = *(const int4*)&ss[w][sbase + j];
      float4 w4 = *(const float4*)&swt[w][sbase + j];
      uint_t ua = *(const uint_t*)&h16[(size_t)s4.x * D + 2 * c];
      uint_t ub = *(const uint_t*)&h16[(size_t)s4.y * D + 2 * c];
      uint_t uc = *(const uint_t*)&h16[(size_t)s4.z * D + 2 * c];
      uint_t ud = *(const uint_t*)&h16[(size_t)s4.w * D + 2 * c];
      acc0 = fmaf(w4.x, b2f_lo(ua), acc0); acc1 = fmaf(w4.x, b2f_hi(ua), acc1);
      acc0 = fmaf(w4.y, b2f_lo(ub), acc0); acc1 = fmaf(w4.y, b2f_hi(ub), acc1);
      acc0 = fmaf(w4.z, b2f_lo(uc), acc0); acc1 = fmaf(w4.z, b2f_hi(uc), acc1);
      acc0 = fmaf(w4.w, b2f_lo(ud), acc0); acc1 = fmaf(w4.w, b2f_hi(ud), acc1);
    }
    for (; j < nm; ++j) {
      int s1 = ss[w][sbase + j];
      float w1 = swt[w][sbase + j];
      uint_t u = *(const uint_t*)&h16[(size_t)s1 * D + 2 * c];
      acc0 = fmaf(w1, b2f_lo(u), acc0);
      acc1 = fmaf(w1, b2f_hi(u), acc1);
    }
    kA += cntA; kB += cntB;
  }
  float2 gb2 = *(const float2*)&gb[2 * c];
  float2 lg2 = *(const float2*)&lg[2 * c];
  float2 lb2 = *(const float2*)&lb[2 * c];
  float2 rs2 = *(const float2*)&res[(size_t)i * D + 2 * c];
  float x0 = silu_f(acc0 + gb2.x) + rs2.x;
  float x1 = silu_f(acc1 + gb2.y) + rs2.y;
  float mu = half_sum32(x0 + x1) * (1.f / 64.f);
  float d0 = x0 - mu, d1 = x1 - mu;
  float var = half_sum32(d0 * d0 + d1 * d1) * (1.f / 64.f);
  float rinv = rsqrtf(var + EPS);
  float o0 = d0 * rinv * lg2.x + lb2.x;
  float o1 = d1 * rinv * lg2.y + lb2.y;
  float2 o2; o2.x = o0; o2.y = o1;
  *(float2*)&x2[(size_t)i * D + 2 * c] = o2;
  uint_t pk = (uint_t)f2b(o0) | ((uint_t)f2b(o1) << 16);
  *(uint_t*)&xt[2 * w + half][2 * c] = pk;
  {
    ushort_t* xz = &xt[8][0];
    for (int e = threadIdx.x; e < 8 * 72; e += 256) xz[e] = 0;
  }
  __syncthreads();
  // GAT node transform: xl = bf16(x2) @ Wg (wave w owns col-tile t=w)
  int t = w;
  int q = l >> 4, cn = l & 15;
  bf16x8 a0 = *(const bf16x8*)&xt[cn][q * 8];
  bf16x8 a1 = *(const bf16x8*)&xt[cn][q * 8 + 32];
  bf16x8 b0 = *(const bf16x8*)&wg[(size_t)((0 * 4 + t) * 512 + l * 8)];
  bf16x8 b1 = *(const bf16x8*)&wg[(size_t)((1 * 4 + t) * 512 + l * 8)];
  f32x4 z = {0.f, 0.f, 0.f, 0.f};
  f32x4 acc = __builtin_amdgcn_mfma_f32_16x16x32_bf16(a0, b0, z, 0, 0, 0);
  acc = __builtin_amdgcn_mfma_f32_16x16x32_bf16(a1, b1, acc, 0, 0, 0);
  if (q < 2) {  // only rows 0..7 are real nodes
    float av = att_src[t * 16 + cn];
    float dv = att_dst[t * 16 + cn];
#pragma unroll
    for (int r = 0; r < 4; ++r) {
      size_t row = (size_t)base + q * 4 + r;
      xl[row * D + t * 16 + cn] = f2b(acc[r]);
      float vs = group_sum16(acc[r] * av);
      float vd = group_sum16(acc[r] * dv);
      if (cn == 0) {
        a_s[row * 4 + t] = vs;
        a_d[row * 4 + t] = vd;
      }
    }
  }
}

// ---------- fused GAT aggregate (+ optional next-layer dual GEMM) ----------
template <int FUSE>
__global__ void __launch_bounds__(256) k_gat_fin(
    const ushort_t* __restrict__ xl16, const float* __restrict__ x2,
    const float* __restrict__ a_s, const float* __restrict__ a_d,
    const int* __restrict__ rs, const uint_t* __restrict__ reca,
    const float* __restrict__ wea, const float* __restrict__ scal,
    const float* __restrict__ bg,
    const ushort_t* __restrict__ wd, const float* __restrict__ b2,
    ushort_t* __restrict__ out1, float* __restrict__ out2,
    float* __restrict__ xout) {
  __shared__ int ss[4][64];
  __shared__ float el[4][4][68];
  __shared__ __align__(16) ushort_t xt[16][72];
  int w = threadIdx.x >> 6;
  int l = threadIdx.x & 63;
  int base = blockIdx.x * 8;
  int half = l >> 5, c = l & 31;
  int iA = base + 2 * w;
  int iB = iA + 1;
  int i = iA + half;
  int hh = c >> 3;  // head of cols 2c,2c+1
  float4 wv4 = *(const float4*)wea;
  float mean_attr = scal[1];
  float we_h = sel4(wv4.x, wv4.y, wv4.z, wv4.w, hh);
  float ad_h = a_d[(size_t)i * 4 + hh];
  float as_i = a_s[(size_t)i * 4 + hh];
  float eS = __expf(lrelu_f(as_i + ad_h + mean_attr * we_h));
  float s = eS;
  uint_t u0 = *(const uint_t*)&xl16[(size_t)i * D + 2 * c];
  float acc0 = eS * b2f_lo(u0);
  float acc1 = eS * b2f_hi(u0);
  float4 ad4 = *(const float4*)(a_d + (size_t)i * 4);
  int kA = rs[iA], kA1 = rs[iA + 1];
  int kB = rs[iB], kB1 = rs[iB + 1];
  int sbase = half * 32;
  while (kA < kA1 || kB < kB1) {
    int cntA = min(32, kA1 - kA);
    int cntB = min(32, kB1 - kB);
    int myk = half ? kB : kA;
    int mycnt = half ? cntB : cntA;
    int src = 0;
    float e0v = 0.f, e1v = 0.f, e2v = 0.f, e3v = 0.f;
    if (c < mycnt) {
      uint_t r = reca[(size_t)(myk + c)];
      src = (int)(r & 0xFFFFu);
      float ea = h2f(r >> 16);
      float4 as4 = *(const float4*)(a_s + (size_t)src * 4);
      e0v = __expf(lrelu_f(as4.x + fmaf(ea, wv4.x, ad4.x)));
      e1v = __expf(lrelu_f(as4.y + fmaf(ea, wv4.y, ad4.y)));
      e2v = __expf(lrelu_f(as4.z + fmaf(ea, wv4.z, ad4.z)));
      e3v = __expf(lrelu_f(as4.w + fmaf(ea, wv4.w, ad4.w)));
    }
    ss[w][l] = src;
    el[w][0][l] = e0v;
    el[w][1][l] = e1v;
    el[w][2][l] = e2v;
    el[w][3][l] = e3v;
    int nm = max(cntA, cntB);
    int j = 0;
    for (; j + 4 <= nm; j += 4) {
      int4 s4 = *(const int4*)&ss[w][sbase + j];
      float4 e4 = *(const float4*)&el[w][hh][sbase + j];
      uint_t ua = *(const uint_t*)&xl16[(size_t)s4.x * D + 2 * c];
      uint_t ub = *(const uint_t*)&xl16[(size_t)s4.y * D + 2 * c];
      uint_t uc = *(const uint_t*)&xl16[(size_t)s4.z * D + 2 * c];
      uint_t ud = *(const uint_t*)&xl16[(size_t)s4.w * D + 2 * c];
      acc0 = fmaf(e4.x, b2f_lo(ua), acc0); acc1 = fmaf(e4.x, b2f_hi(ua), acc1);
      acc0 = fmaf(e4.y, b2f_lo(ub), acc0); acc1 = fmaf(e4.y, b2f_hi(ub), acc1);
      acc0 = fmaf(e4.z, b2f_lo(uc), acc0); acc1 = fmaf(e4.z, b2f_hi(uc), acc1);
      acc0 = fmaf(e4.w, b2f_lo(ud), acc0); acc1 = fmaf(e4.w, b2f_hi(ud), acc1);
      s += (e4.x + e4.y) + (e4.z + e4.w);
    }
    for (; j < nm; ++j) {
      int s1 = ss[w][sbase + j];
      float e1 = el[w][hh][sbase + j];
      uint_t u = *(const uint_t*)&xl16[(size_t)s1 * D + 2 * c];
      acc0 = fmaf(e1, b2f_lo(u), acc0);
      acc1 = fmaf(e1, b2f_hi(u), acc1);
      s += e1;
    }
    kA += cntA; kB += cntB;
  }
  float2 bg2 = *(const float2*)&bg[2 * c];
  float rcp = 1.f / (s + 1e-16f);
  float o0 = acc0 * rcp + bg2.x;
  float o1 = acc1 * rcp + bg2.y;
  float2 x22 = *(const float2*)&x2[(size_t)i * D + 2 * c];
  float v0 = silu_f(o0) + x22.x;
  float v1 = silu_f(o1) + x22.y;
  if (FUSE) {
    // next layer's dual GEMM straight from LDS (xmid never materialized)
    uint_t pk = (uint_t)f2b(v0) | ((uint_t)f2b(v1) << 16);
    *(uint_t*)&xt[2 * w + half][2 * c] = pk;
    {
      ushort_t* xz = &xt[8][0];
      for (int e = threadIdx.x; e < 8 * 72; e += 256) xz[e] = 0;
    }
    __syncthreads();
    int t = w;
    int q = l >> 4, cn = l & 15;
    bf16x8 a0 = *(const bf16x8*)&xt[cn][q * 8];
    bf16x8 a1 = *(const bf16x8*)&xt[cn][q * 8 + 32];
#pragma unroll
    for (int m = 0; m < 2; ++m) {
      bf16x8 b0 = *(const bf16x8*)&wd[(size_t)((m * 8 + 0 * 4 + t) * 512 + l * 8)];
      bf16x8 b1 = *(const bf16x8*)&wd[(size_t)((m * 8 + 1 * 4 + t) * 512 + l * 8)];
      f32x4 z = {0.f, 0.f, 0.f, 0.f};
      f32x4 acc = __builtin_amdgcn_mfma_f32_16x16x32_bf16(a0, b0, z, 0, 0, 0);
      acc = __builtin_amdgcn_mfma_f32_16x16x32_bf16(a1, b1, acc, 0, 0, 0);
      if (q < 2) {
        float bb = (m == 1) ? b2[t * 16 + cn] : 0.f;
#pragma unroll
        for (int r = 0; r < 4; ++r) {
          size_t row = (size_t)base + q * 4 + r;
          if (m == 0)
            out1[row * D + t * 16 + cn] = f2b(acc[r]);
          else
            out2[row * D + t * 16 + cn] = acc[r] + bb;
        }
      }
    }
  } else {
    float2 v2; v2.x = v0; v2.y = v1;
    *(float2*)&xout[(size_t)i * D + 2 * c] = v2;
  }
}

// ---------- launch ----------

extern "C" void kernel_launch(void* const* d_in, const int* in_sizes, int n_in,
                              void* d_out, int out_size, void* d_ws, size_t ws_size,
                              hipStream_t stream) {
  (void)in_sizes; (void)n_in; (void)out_size; (void)ws_size;
  const float* x  = (const float*)d_in[0];
  const int*   ei = (const int*)d_in[1];
  const float* ew = (const float*)d_in[2];
  const float* ea = (const float*)d_in[3];
  const float* P[2][12];
  for (int l = 0; l < 2; ++l)
    for (int j = 0; j < 12; ++j) P[l][j] = (const float*)d_in[4 + l * 12 + j];

  float* W = (float*)d_ws;
  const size_t o_rs    = 0;                          // NN+16 ints
  const size_t o_dinv  = o_rs + NN + 16;             // NN
  const size_t o_wea   = o_dinv + NN;                // 16 (wea2[8] used)
  const size_t o_scal  = o_wea + 16;                 // 1024
  const size_t o_bsum  = o_scal + 1024;              // 256
  const size_t o_hist  = o_bsum + 256;               // STOT ints
  const size_t o_recw  = o_hist + STOT;              // NE uint
  const size_t o_reca  = o_recw + NE;                // NE uint
  const size_t o_rtmp  = o_reca + NE;                // NE uint2
  const size_t o_h16   = o_rtmp + (size_t)NE * 2;    // NN*D ushort
  const size_t o_xl16  = o_h16 + (size_t)NN * D / 2;
  const size_t o_res   = o_xl16 + (size_t)NN * D / 2;
  const size_t o_x2    = o_res + (size_t)NN * D;
  const size_t o_as    = o_x2 + (size_t)NN * D;      // NN*4
  const size_t o_ad    = o_as + (size_t)NN * 4;      // NN*4
  const size_t o_wg16  = o_ad + (size_t)NN * 4;      // 2*4096 ushort (16KB)
  const size_t o_wd16  = o_wg16 + 4096;              // 8192 ushort (16KB)

  int*      rs    = (int*)(W + o_rs);
  float*    dinv  = W + o_dinv;
  float*    wea2  = W + o_wea;
  float*    scal  = W + o_scal;
  int*      bsum  = (int*)(W + o_bsum);
  int*      histG = (int*)(W + o_hist);
  uint_t*   recw  = (uint_t*)(W + o_recw);
  uint_t*   reca  = (uint_t*)(W + o_reca);
  uint2*    rtmp  = (uint2*)(W + o_rtmp);
  ushort_t* h16   = (ushort_t*)(W + o_h16);
  ushort_t* xl16  = (ushort_t*)(W + o_xl16);
  float*    resb  = W + o_res;
  float*    x2b   = W + o_x2;
  float*    asb   = W + o_as;
  float*    adb   = W + o_ad;
  ushort_t* wg16  = (ushort_t*)(W + o_wg16);
  ushort_t* wd16  = (ushort_t*)(W + o_wd16);

  const int B = 256;
  const int gPre = NB1 + (NT + 3) / 4;  // hist blocks + layer0 gemm blocks
  const int gN2  = NN / 8;              // 8 nodes per block (4 waves x 2)

  k_pre<<<gPre, B, 0, stream>>>(ei, histG, x, P[0][0], P[0][2], P[0][3], h16, resb);
  k_scanA<<<SBLK + 1, B, 0, stream>>>(histG, bsum, scal,
                                      P[0][6], P[1][6], P[1][0], P[1][2],
                                      P[0][11], P[0][10], P[1][11], P[1][10],
                                      wg16, wd16, wea2);
  k_scanC<<<SBLK, B, 0, stream>>>(histG, bsum);
  k_part<<<NB1, B, 0, stream>>>(ei, ew, ea, histG, rtmp, scal);
  k_sfin<<<NBIN, B, 0, stream>>>(rtmp, histG, recw, reca, rs, dinv, scal);

  // layer 0
  k_gcn_gat<<<gN2, B, 0, stream>>>(h16, resb, dinv, rs, recw,
                                   P[0][1], P[0][4], P[0][5],
                                   wg16, P[0][8], P[0][9],
                                   x2b, xl16, asb, adb);
  k_gat_fin<1><<<gN2, B, 0, stream>>>(xl16, x2b, asb, adb, rs, reca,
                                      wea2, scal, P[0][7],
                                      wd16, P[1][3], h16, resb, nullptr);
  // layer 1
  k_gcn_gat<<<gN2, B, 0, stream>>>(h16, resb, dinv, rs, recw,
                                   P[1][1], P[1][4], P[1][5],
                                   wg16 + 4096, P[1][8], P[1][9],
                                   x2b, xl16, asb, adb);
  k_gat_fin<0><<<gN2, B, 0, stream>>>(xl16, x2b, asb, adb, rs, reca,
                                      wea2 + 4, scal, P[1][7],
                                      nullptr, nullptr, nullptr, nullptr,
                                      (float*)d_out);
}

// Round 6
// 277.159 us; speedup vs baseline: 1.2808x; 1.0300x over previous
//
#include <hip/hip_runtime.h>
#include <hip/hip_fp16.h>

#define NN 50000
#define NE 800000
#define D 64
#define EPS 1e-5f
#define NT 3125   // NN/16 row-tiles for MFMA GEMMs
#define NB1 250   // partition blocks (NB1*EPB == NE)
#define EPB 3200  // edges per partition block
#define NBIN 196  // coarse bins = ceil(NN/256)
#define STOT 49152  // padded scan length (192*256 >= NBIN*NB1)
#define SBLK 192
#define CAP 5888  // LDS-cached edges per bucket in k_sfing (47 KB)

typedef unsigned short ushort_t;
typedef unsigned int uint_t;
typedef __attribute__((ext_vector_type(8))) short bf16x8;
typedef __attribute__((ext_vector_type(4))) float f32x4;

__device__ __forceinline__ float wave_sum64(float v) {
#pragma unroll
  for (int m = 1; m <= 32; m <<= 1) v += __shfl_xor(v, m, 64);
  return v;
}
__device__ __forceinline__ float half_sum32(float v) {
#pragma unroll
  for (int m = 1; m <= 16; m <<= 1) v += __shfl_xor(v, m, 64);
  return v;
}
__device__ __forceinline__ float group_sum16(float v) {
#pragma unroll
  for (int m = 1; m <= 8; m <<= 1) v += __shfl_xor(v, m, 64);
  return v;
}
__device__ __forceinline__ float silu_f(float v) { return v / (1.f + __expf(-v)); }
__device__ __forceinline__ float lrelu_f(float v) { return v >= 0.f ? v : 0.2f * v; }
__device__ __forceinline__ ushort_t f2b(float x) {
  unsigned u = __float_as_uint(x);
  return (ushort_t)((u + 0x7FFFu + ((u >> 16) & 1u)) >> 16);
}
__device__ __forceinline__ float b2f(ushort_t u) {
  return __uint_as_float(((unsigned)u) << 16);
}
__device__ __forceinline__ float b2f_lo(uint_t u) {
  return __uint_as_float(u << 16);
}
__device__ __forceinline__ float b2f_hi(uint_t u) {
  return __uint_as_float(u & 0xFFFF0000u);
}
__device__ __forceinline__ ushort_t f2h(float x) {
  return __half_as_ushort(__float2half_rn(x));
}
__device__ __forceinline__ float h2f(unsigned u) {
  return __half2float(__ushort_as_half((ushort_t)(u & 0xFFFFu)));
}
__device__ __forceinline__ float sel4(float a, float b, float c, float d, int h) {
  float ab = (h & 1) ? b : a;
  float cd = (h & 1) ? d : c;
  return (h & 2) ? cd : ab;
}
__device__ __forceinline__ bf16x8 pack8(float4 a, float4 b) {
  bf16x8 r;
  r[0] = (short)f2b(a.x); r[1] = (short)f2b(a.y);
  r[2] = (short)f2b(a.z); r[3] = (short)f2b(a.w);
  r[4] = (short)f2b(b.x); r[5] = (short)f2b(b.y);
  r[6] = (short)f2b(b.z); r[7] = (short)f2b(b.w);
  return r;
}

// ---------- coarse histogram ----------
__global__ void __launch_bounds__(256) k_hist(const int* __restrict__ ei,
                                              int* __restrict__ histG) {
  __shared__ int h[NBIN];
  int blk = blockIdx.x;
  for (int j = threadIdx.x; j < NBIN; j += 256) h[j] = 0;
  __syncthreads();
  int e0 = blk * EPB;
  for (int e = e0 + threadIdx.x; e < e0 + EPB; e += 256)
    atomicAdd(&h[ei[NE + e] >> 8], 1);
  __syncthreads();
  for (int j = threadIdx.x; j < NBIN; j += 256) histG[j * NB1 + blk] = h[j];
}

// ---------- scan A: block-local exclusive scan + block sums; block SBLK does
// one-time weight->fragment conversion, wea, scal zeroing ----------
__global__ void __launch_bounds__(256) k_scanA(
    int* __restrict__ histG, int* __restrict__ bsum, float* __restrict__ scal,
    const float* __restrict__ Wg0, const float* __restrict__ Wg1,
    const float* __restrict__ W11, const float* __restrict__ W21,
    const float* __restrict__ We0, const float* __restrict__ ae0,
    const float* __restrict__ We1, const float* __restrict__ ae1,
    ushort_t* __restrict__ wg16, ushort_t* __restrict__ wd16,
    float* __restrict__ wea2) {
  if (blockIdx.x == SBLK) {
    int tid = threadIdx.x;
    for (int t = tid; t < 1024; t += 256) scal[t] = 0.f;
    for (int e = tid; e < 4096; e += 256) {
      int f = e >> 9, r = e & 511;
      int lane = r >> 3, j = r & 7;
      int s = (f >> 2) & 1, t = f & 3;
      int k = s * 32 + (lane >> 4) * 8 + j;
      int n = t * 16 + (lane & 15);
      wg16[e] = f2b(Wg0[k * D + n]);
      wg16[4096 + e] = f2b(Wg1[k * D + n]);
    }
    for (int e = tid; e < 8192; e += 256) {
      int f = e >> 9, r = e & 511;
      int lane = r >> 3, j = r & 7;
      int m = f >> 3, s = (f >> 2) & 1, t = f & 3;
      int k = s * 32 + (lane >> 4) * 8 + j;
      int n = t * 16 + (lane & 15);
      const float* Wm = m ? W21 : W11;
      wd16[e] = f2b(Wm[k * D + n]);
    }
    if (tid < 64) {
      float v = group_sum16(We0[tid] * ae0[tid]);
      if ((tid & 15) == 0) wea2[tid >> 4] = v;
    } else if (tid < 128) {
      int c = tid - 64;
      float v = group_sum16(We1[c] * ae1[c]);
      if ((c & 15) == 0) wea2[4 + (c >> 4)] = v;
    }
    return;
  }
  __shared__ int sm[256];
  int j = threadIdx.x;
  int i = blockIdx.x * 256 + j;
  const int TOT = NBIN * NB1;
  int v = (i < TOT) ? histG[i] : 0;
  sm[j] = v;
  __syncthreads();
  for (int off = 1; off < 256; off <<= 1) {
    int t = (j >= off) ? sm[j - off] : 0;
    __syncthreads();
    sm[j] += t;
    __syncthreads();
  }
  if (i < TOT) histG[i] = sm[j] - v;  // block-local exclusive
  if (j == 255) bsum[blockIdx.x] = sm[255];
}

// Partition pass: derives chunk prefix from raw bsum in-LDS (scanC folded),
// scatters packed temp records via LDS cursors, accumulates edge_attr sum.
__global__ void __launch_bounds__(256) k_part(
    const int* __restrict__ ei, const float* __restrict__ ew,
    const float* __restrict__ ea, const int* __restrict__ histG,
    const int* __restrict__ bsum,
    uint2* __restrict__ rectmp, float* __restrict__ scal) {
  __shared__ int cur[NBIN];
  __shared__ int pex[256];
  int blk = blockIdx.x;
  int t = threadIdx.x;
  // exclusive prefix of bsum[0..SBLK)
  int v0 = (t < SBLK) ? bsum[t] : 0;
  pex[t] = v0;
  __syncthreads();
  for (int off = 1; off < 256; off <<= 1) {
    int u = (t >= off) ? pex[t - off] : 0;
    __syncthreads();
    pex[t] += u;
    __syncthreads();
  }
  int ex0 = pex[t] - v0;
  __syncthreads();
  pex[t] = ex0;
  __syncthreads();
  for (int j = t; j < NBIN; j += 256) {
    int idx = j * NB1 + blk;
    cur[j] = histG[idx] + pex[idx >> 8];
  }
  __syncthreads();
  int e0 = blk * EPB;
  float asum = 0.f;
  for (int e = e0 + t; e < e0 + EPB; e += 256) {
    int src = ei[e];
    int dst = ei[NE + e];
    float w = ew[e];
    float a = ea[e];
    asum += a;
    int slot = atomicAdd(&cur[dst >> 8], 1);
    uint2 r;
    r.x = (uint_t)(src & 0xFFFF) | ((uint_t)f2h(w) << 16);
    r.y = (uint_t)(dst & 0xFF) | ((uint_t)f2h(a) << 16);
    rectmp[slot] = r;
  }
  float s = wave_sum64(asum);
  if ((t & 63) == 0) {
    int slot = (blk * 4 + (t >> 6)) & 63;
    atomicAdd(&scal[(size_t)slot * 16], s);
  }
}

// Final counting sort (blocks 0..NBIN-1): bucket cached in LDS, one global
// read of rectmp. Emits compact split records grouped by dst, rs[], dinv[].
// Blocks >= NBIN run the layer-0 dual GEMM (fills otherwise-idle CUs).
__global__ void __launch_bounds__(256) k_sfing(
    const uint2* __restrict__ rectmp, const int* __restrict__ histG,
    const int* __restrict__ bsum,
    uint_t* __restrict__ recw, uint_t* __restrict__ reca, int* __restrict__ rs,
    float* __restrict__ dinv, float* __restrict__ scal,
    const float* __restrict__ x, const float* __restrict__ W1,
    const float* __restrict__ W2, const float* __restrict__ b2,
    ushort_t* __restrict__ out1, float* __restrict__ out2) {
  __shared__ __align__(16) char smem[4096 + CAP * 8];
  int t = threadIdx.x;
  if (blockIdx.x >= NBIN) {
    // ---- layer-0 dual GEMM role ----
    ushort_t* wf = (ushort_t*)smem;
    for (int e = t; e < 8192; e += 256) {
      int f = e >> 9, r = e & 511;
      int lane = r >> 3, j = r & 7;
      int m = f >> 3, s = (f >> 2) & 1, tt = f & 3;
      int k = s * 32 + (lane >> 4) * 8 + j;
      int n = tt * 16 + (lane & 15);
      const float* Wm = m ? W2 : W1;
      wf[e] = f2b(Wm[k * D + n]);
    }
    __syncthreads();
    int tile = (blockIdx.x - NBIN) * 4 + (t >> 6);
    if (tile >= NT) return;
    int l = t & 63;
    int q = l >> 4, cn = l & 15;
    const float* xr = x + ((size_t)tile * 16 + cn) * D + q * 8;
    float4 xa = *(const float4*)xr;
    float4 xb = *(const float4*)(xr + 4);
    float4 xc = *(const float4*)(xr + 32);
    float4 xd = *(const float4*)(xr + 36);
    bf16x8 a0 = pack8(xa, xb), a1 = pack8(xc, xd);
    f32x4 acc1[4], acc2[4];
#pragma unroll
    for (int tt = 0; tt < 4; ++tt) {
      bf16x8 b10 = *(const bf16x8*)&wf[(0 * 8 + 0 * 4 + tt) * 512 + l * 8];
      bf16x8 b11 = *(const bf16x8*)&wf[(0 * 8 + 1 * 4 + tt) * 512 + l * 8];
      bf16x8 b20 = *(const bf16x8*)&wf[(1 * 8 + 0 * 4 + tt) * 512 + l * 8];
      bf16x8 b21 = *(const bf16x8*)&wf[(1 * 8 + 1 * 4 + tt) * 512 + l * 8];
      f32x4 z = {0.f, 0.f, 0.f, 0.f};
      acc1[tt] = __builtin_amdgcn_mfma_f32_16x16x32_bf16(a0, b10, z, 0, 0, 0);
      acc1[tt] = __builtin_amdgcn_mfma_f32_16x16x32_bf16(a1, b11, acc1[tt], 0, 0, 0);
      acc2[tt] = __builtin_amdgcn_mfma_f32_16x16x32_bf16(a0, b20, z, 0, 0, 0);
      acc2[tt] = __builtin_amdgcn_mfma_f32_16x16x32_bf16(a1, b21, acc2[tt], 0, 0, 0);
    }
#pragma unroll
    for (int tt = 0; tt < 4; ++tt) {
      float bb = b2[tt * 16 + cn];
#pragma unroll
      for (int r = 0; r < 4; ++r) {
        size_t row = (size_t)tile * 16 + q * 4 + r;
        out1[row * D + tt * 16 + cn] = f2b(acc1[tt][r]);
        out2[row * D + tt * 16 + cn] = acc2[tt][r] + bb;
      }
    }
    return;
  }
  // ---- counting-sort role ----
  int* cnt = (int*)smem;
  int* sc  = cnt + 256;
  int* cur = sc + 256;
  float* wsum = (float*)(cur + 256);
  uint2* lrec = (uint2*)(smem + 4096);
  int b = blockIdx.x;
  // exclusive prefix of bsum (scanC folded) via sc
  int v0 = (t < SBLK) ? bsum[t] : 0;
  sc[t] = v0;
  __syncthreads();
  for (int off = 1; off < 256; off <<= 1) {
    int u = (t >= off) ? sc[t - off] : 0;
    __syncthreads();
    sc[t] += u;
    __syncthreads();
  }
  int ex0 = sc[t] - v0;
  __syncthreads();
  sc[t] = ex0;
  __syncthreads();
  int i0 = b * NB1;
  int lo = histG[i0] + sc[i0 >> 8];
  int hi;
  if (b == NBIN - 1) {
    hi = NE;
  } else {
    int i1 = (b + 1) * NB1;
    hi = histG[i1] + sc[i1 >> 8];
  }
  __syncthreads();  // done with sc as prefix buffer
  cnt[t] = 0;
  wsum[t] = 0.f;
  __syncthreads();
  int nc = min(hi - lo, CAP);
  for (int e = t; e < nc; e += 256) lrec[e] = rectmp[lo + e];
  __syncthreads();
  for (int e = t; e < nc; e += 256)
    atomicAdd(&cnt[lrec[e].y & 0xFFu], 1);
  for (int e = lo + CAP + t; e < hi; e += 256)
    atomicAdd(&cnt[rectmp[e].y & 0xFFu], 1);
  __syncthreads();
  int v = cnt[t];
  sc[t] = v;
  __syncthreads();
  for (int off = 1; off < 256; off <<= 1) {
    int u = (t >= off) ? sc[t - off] : 0;
    __syncthreads();
    sc[t] += u;
    __syncthreads();
  }
  int ex = sc[t] - v;  // exclusive within bucket
  int node = b * 256 + t;
  if (node < NN) rs[node] = lo + ex;
  if (b == NBIN - 1 && t == 0) rs[NN] = NE;
  cur[t] = lo + ex;
  __syncthreads();
  for (int e = t; e < nc; e += 256) {
    uint2 r = lrec[e];
    int dl = (int)(r.y & 0xFFu);
    int slot = atomicAdd(&cur[dl], 1);
    atomicAdd(&wsum[dl], h2f(r.x >> 16));
    uint_t src = r.x & 0xFFFFu;
    recw[slot] = r.x;                         // src | f16(w)<<16
    reca[slot] = src | (r.y & 0xFFFF0000u);   // src | f16(ea)<<16
  }
  for (int e = lo + CAP + t; e < hi; e += 256) {
    uint2 r = rectmp[e];
    int dl = (int)(r.y & 0xFFu);
    int slot = atomicAdd(&cur[dl], 1);
    atomicAdd(&wsum[dl], h2f(r.x >> 16));
    uint_t src = r.x & 0xFFFFu;
    recw[slot] = r.x;
    reca[slot] = src | (r.y & 0xFFFF0000u);
  }
  __syncthreads();
  if (node < NN) dinv[node] = rsqrtf(1.f + wsum[t]);
  if (b == 0 && t == 0) {
    float s = 0.f;
    for (int j = 0; j < 64; ++j) s += scal[(size_t)j * 16];
    scal[1] = s / (float)NE;
  }
}

// ---------- fused GCN aggregate + LN + GAT node transform ----------
// 4 waves/block, 2 nodes/wave (half-wave per node, 2 cols/lane).
__global__ void __launch_bounds__(256) k_gcn_gat(
    const ushort_t* __restrict__ h16, const float* __restrict__ res,
    const float* __restrict__ dinv, const int* __restrict__ rs,
    const uint_t* __restrict__ recw,
    const float* __restrict__ gb, const float* __restrict__ lg,
    const float* __restrict__ lb,
    const ushort_t* __restrict__ wg, const float* __restrict__ att_src,
    const float* __restrict__ att_dst,
    float* __restrict__ x2, ushort_t* __restrict__ xl,
    float* __restrict__ a_s, float* __restrict__ a_d) {
  __shared__ int ss[4][64];
  __shared__ float swt[4][64];
  __shared__ __align__(16) ushort_t xt[16][72];  // 144B row stride
  int w = threadIdx.x >> 6;
  int l = threadIdx.x & 63;
  int base = blockIdx.x * 8;
  int half = l >> 5, c = l & 31;   // half: 0=node A, 1=node B; cols 2c,2c+1
  int iA = base + 2 * w;
  int iB = iA + 1;
  int i = iA + half;
  float di = dinv[i];
  uint_t u0 = *(const uint_t*)&h16[(size_t)i * D + 2 * c];
  float dii = di * di;
  float acc0 = dii * b2f_lo(u0);
  float acc1 = dii * b2f_hi(u0);
  int kA = rs[iA], kA1 = rs[iA + 1];
  int kB = rs[iB], kB1 = rs[iB + 1];
  int sbase = half * 32;
  while (kA < kA1 || kB < kB1) {
    int cntA = min(32, kA1 - kA);
    int cntB = min(32, kB1 - kB);
    int myk = half ? kB : kA;
    int mycnt = half ? cntB : cntA;
    int src = 0; float wn = 0.f;
    if (c < mycnt) {
      uint_t r = recw[(size_t)(myk + c)];
      src = (int)(r & 0xFFFFu);
      wn = dinv[src] * h2f(r >> 16) * di;
    }
    ss[w][l] = src;
    swt[w][l] = wn;
    int nm = max(cntA, cntB);
    int j = 0;
    for (; j + 4 <= nm; j += 4) {
      int4 s4 = *(const int4*)&ss[w][sbase + j];
      float4 w4 = *(const float4*)&swt[w][sbase + j];
      uint_t ua = *(const uint_t*)&h16[(size_t)s4.x * D + 2 * c];
      uint_t ub = *(const uint_t*)&h16[(size_t)s4.y * D + 2 * c];
      uint_t uc = *(const uint_t*)&h16[(size_t)s4.z * D + 2 * c];
      uint_t ud = *(const uint_t*)&h16[(size_t)s4.w * D + 2 * c];
      acc0 = fmaf(w4.x, b2f_lo(ua), acc0); acc1 = fmaf(w4.x, b2f_hi(ua), acc1);
      acc0 = fmaf(w4.y, b2f_lo(ub), acc0); acc1 = fmaf(w4.y, b2f_hi(ub), acc1);
      acc0 = fmaf(w4.z, b2f_lo(uc), acc0); acc1 = fmaf(w4.z, b2f_hi(uc), acc1);
      acc0 = fmaf(w4.w, b2f_lo(ud), acc0); acc1 = fmaf(w4.w, b2f_hi(ud), acc1);
    }
    for (; j < nm; ++j) {
      int s1 = ss[w][sbase + j];
      float w1 = swt[w][sbase + j];
      uint_t u = *(const uint_t*)&h16[(size_t)s1 * D + 2 * c];
      acc0 = fmaf(w1, b2f_lo(u), acc0);
      acc1 = fmaf(w1, b2f_hi(u), acc1);
    }
    kA += cntA; kB += cntB;
  }
  float2 gb2 = *(const float2*)&gb[2 * c];
  float2 lg2 = *(const float2*)&lg[2 * c];
  float2 lb2 = *(const float2*)&lb[2 * c];
  float2 rs2 = *(const float2*)&res[(size_t)i * D + 2 * c];
  float x0 = silu_f(acc0 + gb2.x) + rs2.x;
  float x1 = silu_f(acc1 + gb2.y) + rs2.y;
  float mu = half_sum32(x0 + x1) * (1.f / 64.f);
  float d0 = x0 - mu, d1 = x1 - mu;
  float var = half_sum32(d0 * d0 + d1 * d1) * (1.f / 64.f);
  float rinv = rsqrtf(var + EPS);
  float o0 = d0 * rinv * lg2.x + lb2.x;
  float o1 = d1 * rinv * lg2.y + lb2.y;
  float2 o2; o2.x = o0; o2.y = o1;
  *(float2*)&x2[(size_t)i * D + 2 * c] = o2;
  uint_t pk = (uint_t)f2b(o0) | ((uint_t)f2b(o1) << 16);
  *(uint_t*)&xt[2 * w + half][2 * c] = pk;
  {
    ushort_t* xz = &xt[8][0];
    for (int e = threadIdx.x; e < 8 * 72; e += 256) xz[e] = 0;
  }
  __syncthreads();
  // GAT node transform: xl = bf16(x2) @ Wg (wave w owns col-tile t=w)
  int t = w;
  int q = l >> 4, cn = l & 15;
  bf16x8 a0 = *(const bf16x8*)&xt[cn][q * 8];
  bf16x8 a1 = *(const bf16x8*)&xt[cn][q * 8 + 32];
  bf16x8 b0 = *(const bf16x8*)&wg[(size_t)((0 * 4 + t) * 512 + l * 8)];
  bf16x8 b1 = *(const bf16x8*)&wg[(size_t)((1 * 4 + t) * 512 + l * 8)];
  f32x4 z = {0.f, 0.f, 0.f, 0.f};
  f32x4 acc = __builtin_amdgcn_mfma_f32_16x16x32_bf16(a0, b0, z, 0, 0, 0);
  acc = __builtin_amdgcn_mfma_f32_16x16x32_bf16(a1, b1, acc, 0, 0, 0);
  if (q < 2) {  // only rows 0..7 are real nodes
    float av = att_src[t * 16 + cn];
    float dv = att_dst[t * 16 + cn];
#pragma unroll
    for (int r = 0; r < 4; ++r) {
      size_t row = (size_t)base + q * 4 + r;
      xl[row * D + t * 16 + cn] = f2b(acc[r]);
      float vs = group_sum16(acc[r] * av);
      float vd = group_sum16(acc[r] * dv);
      if (cn == 0) {
        a_s[row * 4 + t] = vs;
        a_d[row * 4 + t] = vd;
      }
    }
  }
}

// ---------- fused GAT aggregate (+ optional next-layer dual GEMM) ----------
template <int FUSE>
__global__ void __launch_bounds__(256) k_gat_fin(
    const ushort_t* __restrict__ xl16, const float* __restrict__ x2,
    const float* __restrict__ a_s, const float* __restrict__ a_d,
    const int* __restrict__ rs, const uint_t* __restrict__ reca,
    const float* __restrict__ wea, const float* __restrict__ scal,
    const float* __restrict__ bg,
    const ushort_t* __restrict__ wd, const float* __restrict__ b2,
    ushort_t* __restrict__ out1, float* __restrict__ out2,
    float* __restrict__ xout) {
  __shared__ int ss[4][64];
  __shared__ float el[4][4][68];
  __shared__ __align__(16) ushort_t xt[16][72];
  int w = threadIdx.x >> 6;
  int l = threadIdx.x & 63;
  int base = blockIdx.x * 8;
  int half = l >> 5, c = l & 31;
  int iA = base + 2 * w;
  int iB = iA + 1;
  int i = iA + half;
  int hh = c >> 3;  // head of cols 2c,2c+1
  float4 wv4 = *(const float4*)wea;
  float mean_attr = scal[1];
  float we_h = sel4(wv4.x, wv4.y, wv4.z, wv4.w, hh);
  float ad_h = a_d[(size_t)i * 4 + hh];
  float as_i = a_s[(size_t)i * 4 + hh];
  float eS = __expf(lrelu_f(as_i + ad_h + mean_attr * we_h));
  float s = eS;
  uint_t u0 = *(const uint_t*)&xl16[(size_t)i * D + 2 * c];
  float acc0 = eS * b2f_lo(u0);
  float acc1 = eS * b2f_hi(u0);
  float4 ad4 = *(const float4*)(a_d + (size_t)i * 4);
  int kA = rs[iA], kA1 = rs[iA + 1];
  int kB = rs[iB], kB1 = rs[iB + 1];
  int sbase = half * 32;
  while (kA < kA1 || kB < kB1) {
    int cntA = min(32, kA1 - kA);
    int cntB = min(32, kB1 - kB);
    int myk = half ? kB : kA;
    int mycnt = half ? cntB : cntA;
    int src = 0;
    float e0v = 0.f, e1v = 0.f, e2v = 0.f, e3v = 0.f;
    if (c < mycnt) {
      uint_t r = reca[(size_t)(myk + c)];
      src = (int)(r & 0xFFFFu);
      float ea = h2f(r >> 16);
      float4 as4 = *(const float4*)(a_s + (size_t)src * 4);
      e0v = __expf(lrelu_f(as4.x + fmaf(ea, wv4.x, ad4.x)));
      e1v = __expf(lrelu_f(as4.y + fmaf(ea, wv4.y, ad4.y)));
      e2v = __expf(lrelu_f(as4.z + fmaf(ea, wv4.z, ad4.z)));
      e3v = __expf(lrelu_f(as4.w + fmaf(ea, wv4.w, ad4.w)));
    }
    ss[w][l] = src;
    el[w][0][l] = e0v;
    el[w][1][l] = e1v;
    el[w][2][l] = e2v;
    el[w][3][l] = e3v;
    int nm = max(cntA, cntB);
    int j = 0;
    for (; j + 4 <= nm; j += 4) {
      int4 s4 = *(const int4*)&ss[w][sbase + j];
      float4 e4 = *(const float4*)&el[w][hh][sbase + j];
      uint_t ua = *(const uint_t*)&xl16[(size_t)s4.x * D + 2 * c];
      uint_t ub = *(const uint_t*)&xl16[(size_t)s4.y * D + 2 * c];
      uint_t uc = *(const uint_t*)&xl16[(size_t)s4.z * D + 2 * c];
      uint_t ud = *(const uint_t*)&xl16[(size_t)s4.w * D + 2 * c];
      acc0 = fmaf(e4.x, b2f_lo(ua), acc0); acc1 = fmaf(e4.x, b2f_hi(ua), acc1);
      acc0 = fmaf(e4.y, b2f_lo(ub), acc0); acc1 = fmaf(e4.y, b2f_hi(ub), acc1);
      acc0 = fmaf(e4.z, b2f_lo(uc), acc0); acc1 = fmaf(e4.z, b2f_hi(uc), acc1);
      acc0 = fmaf(e4.w, b2f_lo(ud), acc0); acc1 = fmaf(e4.w, b2f_hi(ud), acc1);
      s += (e4.x + e4.y) + (e4.z + e4.w);
    }
    for (; j < nm; ++j) {
      int s1 = ss[w][sbase + j];
      float e1 = el[w][hh][sbase + j];
      uint_t u = *(const uint_t*)&xl16[(size_t)s1 * D + 2 * c];
      acc0 = fmaf(e1, b2f_lo(u), acc0);
      acc1 = fmaf(e1, b2f_hi(u), acc1);
      s += e1;
    }
    kA += cntA; kB += cntB;
  }
  float2 bg2 = *(const float2*)&bg[2 * c];
  float rcp = 1.f / (s + 1e-16f);
  float o0 = acc0 * rcp + bg2.x;
  float o1 = acc1 * rcp + bg2.y;
  float2 x22 = *(const float2*)&x2[(size_t)i * D + 2 * c];
  float v0 = silu_f(o0) + x22.x;
  float v1 = silu_f(o1) + x22.y;
  if (FUSE) {
    // next layer's dual GEMM straight from LDS (xmid never materialized)
    uint_t pk = (uint_t)f2b(v0) | ((uint_t)f2b(v1) << 16);
    *(uint_t*)&xt[2 * w + half][2 * c] = pk;
    {
      ushort_t* xz = &xt[8][0];
      for (int e = threadIdx.x; e < 8 * 72; e += 256) xz[e] = 0;
    }
    __syncthreads();
    int t = w;
    int q = l >> 4, cn = l & 15;
    bf16x8 a0 = *(const bf16x8*)&xt[cn][q * 8];
    bf16x8 a1 = *(const bf16x8*)&xt[cn][q * 8 + 32];
#pragma unroll
    for (int m = 0; m < 2; ++m) {
      bf16x8 b0 = *(const bf16x8*)&wd[(size_t)((m * 8 + 0 * 4 + t) * 512 + l * 8)];
      bf16x8 b1 = *(const bf16x8*)&wd[(size_t)((m * 8 + 1 * 4 + t) * 512 + l * 8)];
      f32x4 z = {0.f, 0.f, 0.f, 0.f};
      f32x4 acc = __builtin_amdgcn_mfma_f32_16x16x32_bf16(a0, b0, z, 0, 0, 0);
      acc = __builtin_amdgcn_mfma_f32_16x16x32_bf16(a1, b1, acc, 0, 0, 0);
      if (q < 2) {
        float bb = (m == 1) ? b2[t * 16 + cn] : 0.f;
#pragma unroll
        for (int r = 0; r < 4; ++r) {
          size_t row = (size_t)base + q * 4 + r;
          if (m == 0)
            out1[row * D + t * 16 + cn] = f2b(acc[r]);
          else
            out2[row * D + t * 16 + cn] = acc[r] + bb;
        }
      }
    }
  } else {
    float2 v2; v2.x = v0; v2.y = v1;
    *(float2*)&xout[(size_t)i * D + 2 * c] = v2;
  }
}

// ---------- launch ----------

extern "C" void kernel_launch(void* const* d_in, const int* in_sizes, int n_in,
                              void* d_out, int out_size, void* d_ws, size_t ws_size,
                              hipStream_t stream) {
  (void)in_sizes; (void)n_in; (void)out_size; (void)ws_size;
  const float* x  = (const float*)d_in[0];
  const int*   ei = (const int*)d_in[1];
  const float* ew = (const float*)d_in[2];
  const float* ea = (const float*)d_in[3];
  const float* P[2][12];
  for (int l = 0; l < 2; ++l)
    for (int j = 0; j < 12; ++j) P[l][j] = (const float*)d_in[4 + l * 12 + j];

  float* W = (float*)d_ws;
  const size_t o_rs    = 0;                          // NN+16 ints
  const size_t o_dinv  = o_rs + NN + 16;             // NN
  const size_t o_wea   = o_dinv + NN;                // 16 (wea2[8] used)
  const size_t o_scal  = o_wea + 16;                 // 1024
  const size_t o_bsum  = o_scal + 1024;              // 256
  const size_t o_hist  = o_bsum + 256;               // STOT ints
  const size_t o_recw  = o_hist + STOT;              // NE uint
  const size_t o_reca  = o_recw + NE;                // NE uint
  const size_t o_rtmp  = o_reca + NE;                // NE uint2
  const size_t o_h16   = o_rtmp + (size_t)NE * 2;    // NN*D ushort
  const size_t o_xl16  = o_h16 + (size_t)NN * D / 2;
  const size_t o_res   = o_xl16 + (size_t)NN * D / 2;
  const size_t o_x2    = o_res + (size_t)NN * D;
  const size_t o_as    = o_x2 + (size_t)NN * D;      // NN*4
  const size_t o_ad    = o_as + (size_t)NN * 4;      // NN*4
  const size_t o_wg16  = o_ad + (size_t)NN * 4;      // 2*4096 ushort (16KB)
  const size_t o_wd16  = o_wg16 + 4096;              // 8192 ushort (16KB)

  int*      rs    = (int*)(W + o_rs);
  float*    dinv  = W + o_dinv;
  float*    wea2  = W + o_wea;
  float*    scal  = W + o_scal;
  int*      bsum  = (int*)(W + o_bsum);
  int*      histG = (int*)(W + o_hist);
  uint_t*   recw  = (uint_t*)(W + o_recw);
  uint_t*   reca  = (uint_t*)(W + o_reca);
  uint2*    rtmp  = (uint2*)(W + o_rtmp);
  ushort_t* h16   = (ushort_t*)(W + o_h16);
  ushort_t* xl16  = (ushort_t*)(W + o_xl16);
  float*    resb  = W + o_res;
  float*    x2b   = W + o_x2;
  float*    asb   = W + o_as;
  float*    adb   = W + o_ad;
  ushort_t* wg16  = (ushort_t*)(W + o_wg16);
  ushort_t* wd16  = (ushort_t*)(W + o_wd16);

  const int B = 256;
  const int gSf = NBIN + (NT + 3) / 4;  // sort buckets + layer0 gemm blocks
  const int gN2 = NN / 8;               // 8 nodes per block (4 waves x 2)

  k_hist<<<NB1, B, 0, stream>>>(ei, histG);
  k_scanA<<<SBLK + 1, B, 0, stream>>>(histG, bsum, scal,
                                      P[0][6], P[1][6], P[1][0], P[1][2],
                                      P[0][11], P[0][10], P[1][11], P[1][10],
                                      wg16, wd16, wea2);
  k_part<<<NB1, B, 0, stream>>>(ei, ew, ea, histG, bsum, rtmp, scal);
  k_sfing<<<gSf, B, 0, stream>>>(rtmp, histG, bsum, recw, reca, rs, dinv, scal,
                                 x, P[0][0], P[0][2], P[0][3], h16, resb);

  // layer 0
  k_gcn_gat<<<gN2, B, 0, stream>>>(h16, resb, dinv, rs, recw,
                                   P[0][1], P[0][4], P[0][5],
                                   wg16, P[0][8], P[0][9],
                                   x2b, xl16, asb, adb);
  k_gat_fin<1><<<gN2, B, 0, stream>>>(xl16, x2b, asb, adb, rs, reca,
                                      wea2, scal, P[0][7],
                                      wd16, P[1][3], h16, resb, nullptr);
  // layer 1
  k_gcn_gat<<<gN2, B, 0, stream>>>(h16, resb, dinv, rs, recw,
                                   P[1][1], P[1][4], P[1][5],
                                   wg16 + 4096, P[1][8], P[1][9],
                                   x2b, xl16, asb, adb);
  k_gat_fin<0><<<gN2, B, 0, stream>>>(xl16, x2b, asb, adb, rs, reca,
                                      wea2 + 4, scal, P[1][7],
                                      nullptr, nullptr, nullptr, nullptr,
                                      (float*)d_out);
}

// Round 7
// 261.661 us; speedup vs baseline: 1.3567x; 1.0592x over previous
//
#include <hip/hip_runtime.h>
#include <hip/hip_fp16.h>

#define NN 50000
#define NE 800000
#define D 64
#define EPS 1e-5f
#define NT 3125   // NN/16 row-tiles for MFMA GEMMs
#define NB1 250   // partition blocks (NB1*EPB == NE)
#define EPB 3200  // edges per partition block
#define NBIN 196  // coarse bins = ceil(NN/256)
#define STOT 49152  // padded scan length (192*256 >= NBIN*NB1)
#define SBLK 192
#define CAP 5888  // LDS-cached edges per bucket in k_sfing (47 KB)

typedef unsigned short ushort_t;
typedef unsigned int uint_t;
typedef __attribute__((ext_vector_type(8))) short bf16x8;
typedef __attribute__((ext_vector_type(4))) float f32x4;

__device__ __forceinline__ float wave_sum64(float v) {
#pragma unroll
  for (int m = 1; m <= 32; m <<= 1) v += __shfl_xor(v, m, 64);
  return v;
}
__device__ __forceinline__ float half_sum32(float v) {
#pragma unroll
  for (int m = 1; m <= 16; m <<= 1) v += __shfl_xor(v, m, 64);
  return v;
}
__device__ __forceinline__ float group_sum16(float v) {
#pragma unroll
  for (int m = 1; m <= 8; m <<= 1) v += __shfl_xor(v, m, 64);
  return v;
}
__device__ __forceinline__ float silu_f(float v) { return v / (1.f + __expf(-v)); }
__device__ __forceinline__ float lrelu_f(float v) { return v >= 0.f ? v : 0.2f * v; }
__device__ __forceinline__ ushort_t f2b(float x) {
  unsigned u = __float_as_uint(x);
  return (ushort_t)((u + 0x7FFFu + ((u >> 16) & 1u)) >> 16);
}
__device__ __forceinline__ float b2f(ushort_t u) {
  return __uint_as_float(((unsigned)u) << 16);
}
__device__ __forceinline__ float b2f_lo(uint_t u) {
  return __uint_as_float(u << 16);
}
__device__ __forceinline__ float b2f_hi(uint_t u) {
  return __uint_as_float(u & 0xFFFF0000u);
}
__device__ __forceinline__ ushort_t f2h(float x) {
  return __half_as_ushort(__float2half_rn(x));
}
__device__ __forceinline__ float h2f(unsigned u) {
  return __half2float(__ushort_as_half((ushort_t)(u & 0xFFFFu)));
}
__device__ __forceinline__ float sel4(float a, float b, float c, float d, int h) {
  float ab = (h & 1) ? b : a;
  float cd = (h & 1) ? d : c;
  return (h & 2) ? cd : ab;
}
__device__ __forceinline__ bf16x8 pack8(float4 a, float4 b) {
  bf16x8 r;
  r[0] = (short)f2b(a.x); r[1] = (short)f2b(a.y);
  r[2] = (short)f2b(a.z); r[3] = (short)f2b(a.w);
  r[4] = (short)f2b(b.x); r[5] = (short)f2b(b.y);
  r[6] = (short)f2b(b.z); r[7] = (short)f2b(b.w);
  return r;
}

// ---------- coarse histogram ----------
__global__ void __launch_bounds__(256) k_hist(const int* __restrict__ ei,
                                              int* __restrict__ histG) {
  __shared__ int h[NBIN];
  int blk = blockIdx.x;
  for (int j = threadIdx.x; j < NBIN; j += 256) h[j] = 0;
  __syncthreads();
  int e0 = blk * EPB;
  for (int e = e0 + threadIdx.x; e < e0 + EPB; e += 256)
    atomicAdd(&h[ei[NE + e] >> 8], 1);
  __syncthreads();
  for (int j = threadIdx.x; j < NBIN; j += 256) histG[j * NB1 + blk] = h[j];
}

// ---------- scan A: block-local exclusive scan + block sums; block SBLK does
// one-time weight->fragment conversion, wea, scal zeroing ----------
__global__ void __launch_bounds__(256) k_scanA(
    int* __restrict__ histG, int* __restrict__ bsum, float* __restrict__ scal,
    const float* __restrict__ Wg0, const float* __restrict__ Wg1,
    const float* __restrict__ W11, const float* __restrict__ W21,
    const float* __restrict__ We0, const float* __restrict__ ae0,
    const float* __restrict__ We1, const float* __restrict__ ae1,
    ushort_t* __restrict__ wg16, ushort_t* __restrict__ wd16,
    float* __restrict__ wea2) {
  if (blockIdx.x == SBLK) {
    int tid = threadIdx.x;
    for (int t = tid; t < 1024; t += 256) scal[t] = 0.f;
    for (int e = tid; e < 4096; e += 256) {
      int f = e >> 9, r = e & 511;
      int lane = r >> 3, j = r & 7;
      int s = (f >> 2) & 1, t = f & 3;
      int k = s * 32 + (lane >> 4) * 8 + j;
      int n = t * 16 + (lane & 15);
      wg16[e] = f2b(Wg0[k * D + n]);
      wg16[4096 + e] = f2b(Wg1[k * D + n]);
    }
    for (int e = tid; e < 8192; e += 256) {
      int f = e >> 9, r = e & 511;
      int lane = r >> 3, j = r & 7;
      int m = f >> 3, s = (f >> 2) & 1, t = f & 3;
      int k = s * 32 + (lane >> 4) * 8 + j;
      int n = t * 16 + (lane & 15);
      const float* Wm = m ? W21 : W11;
      wd16[e] = f2b(Wm[k * D + n]);
    }
    if (tid < 64) {
      float v = group_sum16(We0[tid] * ae0[tid]);
      if ((tid & 15) == 0) wea2[tid >> 4] = v;
    } else if (tid < 128) {
      int c = tid - 64;
      float v = group_sum16(We1[c] * ae1[c]);
      if ((c & 15) == 0) wea2[4 + (c >> 4)] = v;
    }
    return;
  }
  __shared__ int sm[256];
  int j = threadIdx.x;
  int i = blockIdx.x * 256 + j;
  const int TOT = NBIN * NB1;
  int v = (i < TOT) ? histG[i] : 0;
  sm[j] = v;
  __syncthreads();
  for (int off = 1; off < 256; off <<= 1) {
    int t = (j >= off) ? sm[j - off] : 0;
    __syncthreads();
    sm[j] += t;
    __syncthreads();
  }
  if (i < TOT) histG[i] = sm[j] - v;  // block-local exclusive
  if (j == 255) bsum[blockIdx.x] = sm[255];
}

// Partition pass: derives chunk prefix from raw bsum in-LDS (scanC folded),
// scatters packed temp records via LDS cursors, accumulates edge_attr sum.
__global__ void __launch_bounds__(256) k_part(
    const int* __restrict__ ei, const float* __restrict__ ew,
    const float* __restrict__ ea, const int* __restrict__ histG,
    const int* __restrict__ bsum,
    uint2* __restrict__ rectmp, float* __restrict__ scal) {
  __shared__ int cur[NBIN];
  __shared__ int pex[256];
  int blk = blockIdx.x;
  int t = threadIdx.x;
  // exclusive prefix of bsum[0..SBLK)
  int v0 = (t < SBLK) ? bsum[t] : 0;
  pex[t] = v0;
  __syncthreads();
  for (int off = 1; off < 256; off <<= 1) {
    int u = (t >= off) ? pex[t - off] : 0;
    __syncthreads();
    pex[t] += u;
    __syncthreads();
  }
  int ex0 = pex[t] - v0;
  __syncthreads();
  pex[t] = ex0;
  __syncthreads();
  for (int j = t; j < NBIN; j += 256) {
    int idx = j * NB1 + blk;
    cur[j] = histG[idx] + pex[idx >> 8];
  }
  __syncthreads();
  int e0 = blk * EPB;
  float asum = 0.f;
  for (int e = e0 + t; e < e0 + EPB; e += 256) {
    int src = ei[e];
    int dst = ei[NE + e];
    float w = ew[e];
    float a = ea[e];
    asum += a;
    int slot = atomicAdd(&cur[dst >> 8], 1);
    uint2 r;
    r.x = (uint_t)(src & 0xFFFF) | ((uint_t)f2h(w) << 16);
    r.y = (uint_t)(dst & 0xFF) | ((uint_t)f2h(a) << 16);
    rectmp[slot] = r;
  }
  float s = wave_sum64(asum);
  if ((t & 63) == 0) {
    int slot = (blk * 4 + (t >> 6)) & 63;
    atomicAdd(&scal[(size_t)slot * 16], s);
  }
}

// Final counting sort (blocks 0..NBIN-1): bucket cached in LDS, one global
// read of rectmp. Emits compact split records grouped by dst, rs[], dinv[].
// Blocks >= NBIN run the layer-0 dual GEMM (fills otherwise-idle CUs).
__global__ void __launch_bounds__(256) k_sfing(
    const uint2* __restrict__ rectmp, const int* __restrict__ histG,
    const int* __restrict__ bsum,
    uint_t* __restrict__ recw, uint_t* __restrict__ reca, int* __restrict__ rs,
    float* __restrict__ dinv, float* __restrict__ scal,
    const float* __restrict__ x, const float* __restrict__ W1,
    const float* __restrict__ W2, const float* __restrict__ b2,
    ushort_t* __restrict__ out1, float* __restrict__ out2) {
  __shared__ __align__(16) char smem[4096 + CAP * 8];
  int t = threadIdx.x;
  if (blockIdx.x >= NBIN) {
    // ---- layer-0 dual GEMM role ----
    ushort_t* wf = (ushort_t*)smem;
    for (int e = t; e < 8192; e += 256) {
      int f = e >> 9, r = e & 511;
      int lane = r >> 3, j = r & 7;
      int m = f >> 3, s = (f >> 2) & 1, tt = f & 3;
      int k = s * 32 + (lane >> 4) * 8 + j;
      int n = tt * 16 + (lane & 15);
      const float* Wm = m ? W2 : W1;
      wf[e] = f2b(Wm[k * D + n]);
    }
    __syncthreads();
    int tile = (blockIdx.x - NBIN) * 4 + (t >> 6);
    if (tile >= NT) return;
    int l = t & 63;
    int q = l >> 4, cn = l & 15;
    const float* xr = x + ((size_t)tile * 16 + cn) * D + q * 8;
    float4 xa = *(const float4*)xr;
    float4 xb = *(const float4*)(xr + 4);
    float4 xc = *(const float4*)(xr + 32);
    float4 xd = *(const float4*)(xr + 36);
    bf16x8 a0 = pack8(xa, xb), a1 = pack8(xc, xd);
    f32x4 acc1[4], acc2[4];
#pragma unroll
    for (int tt = 0; tt < 4; ++tt) {
      bf16x8 b10 = *(const bf16x8*)&wf[(0 * 8 + 0 * 4 + tt) * 512 + l * 8];
      bf16x8 b11 = *(const bf16x8*)&wf[(0 * 8 + 1 * 4 + tt) * 512 + l * 8];
      bf16x8 b20 = *(const bf16x8*)&wf[(1 * 8 + 0 * 4 + tt) * 512 + l * 8];
      bf16x8 b21 = *(const bf16x8*)&wf[(1 * 8 + 1 * 4 + tt) * 512 + l * 8];
      f32x4 z = {0.f, 0.f, 0.f, 0.f};
      acc1[tt] = __builtin_amdgcn_mfma_f32_16x16x32_bf16(a0, b10, z, 0, 0, 0);
      acc1[tt] = __builtin_amdgcn_mfma_f32_16x16x32_bf16(a1, b11, acc1[tt], 0, 0, 0);
      acc2[tt] = __builtin_amdgcn_mfma_f32_16x16x32_bf16(a0, b20, z, 0, 0, 0);
      acc2[tt] = __builtin_amdgcn_mfma_f32_16x16x32_bf16(a1, b21, acc2[tt], 0, 0, 0);
    }
#pragma unroll
    for (int tt = 0; tt < 4; ++tt) {
      float bb = b2[tt * 16 + cn];
#pragma unroll
      for (int r = 0; r < 4; ++r) {
        size_t row = (size_t)tile * 16 + q * 4 + r;
        out1[row * D + tt * 16 + cn] = f2b(acc1[tt][r]);
        out2[row * D + tt * 16 + cn] = acc2[tt][r] + bb;
      }
    }
    return;
  }
  // ---- counting-sort role ----
  int* cnt = (int*)smem;
  int* sc  = cnt + 256;
  int* cur = sc + 256;
  float* wsum = (float*)(cur + 256);
  uint2* lrec = (uint2*)(smem + 4096);
  int b = blockIdx.x;
  // exclusive prefix of bsum (scanC folded) via sc
  int v0 = (t < SBLK) ? bsum[t] : 0;
  sc[t] = v0;
  __syncthreads();
  for (int off = 1; off < 256; off <<= 1) {
    int u = (t >= off) ? sc[t - off] : 0;
    __syncthreads();
    sc[t] += u;
    __syncthreads();
  }
  int ex0 = sc[t] - v0;
  __syncthreads();
  sc[t] = ex0;
  __syncthreads();
  int i0 = b * NB1;
  int lo = histG[i0] + sc[i0 >> 8];
  int hi;
  if (b == NBIN - 1) {
    hi = NE;
  } else {
    int i1 = (b + 1) * NB1;
    hi = histG[i1] + sc[i1 >> 8];
  }
  __syncthreads();  // done with sc as prefix buffer
  cnt[t] = 0;
  wsum[t] = 0.f;
  __syncthreads();
  int nc = min(hi - lo, CAP);
  for (int e = t; e < nc; e += 256) lrec[e] = rectmp[lo + e];
  __syncthreads();
  for (int e = t; e < nc; e += 256)
    atomicAdd(&cnt[lrec[e].y & 0xFFu], 1);
  for (int e = lo + CAP + t; e < hi; e += 256)
    atomicAdd(&cnt[rectmp[e].y & 0xFFu], 1);
  __syncthreads();
  int v = cnt[t];
  sc[t] = v;
  __syncthreads();
  for (int off = 1; off < 256; off <<= 1) {
    int u = (t >= off) ? sc[t - off] : 0;
    __syncthreads();
    sc[t] += u;
    __syncthreads();
  }
  int ex = sc[t] - v;  // exclusive within bucket
  int node = b * 256 + t;
  if (node < NN) rs[node] = lo + ex;
  if (b == NBIN - 1 && t == 0) rs[NN] = NE;
  cur[t] = lo + ex;
  __syncthreads();
  for (int e = t; e < nc; e += 256) {
    uint2 r = lrec[e];
    int dl = (int)(r.y & 0xFFu);
    int slot = atomicAdd(&cur[dl], 1);
    atomicAdd(&wsum[dl], h2f(r.x >> 16));
    uint_t src = r.x & 0xFFFFu;
    recw[slot] = r.x;                         // src | f16(w)<<16
    reca[slot] = src | (r.y & 0xFFFF0000u);   // src | f16(ea)<<16
  }
  for (int e = lo + CAP + t; e < hi; e += 256) {
    uint2 r = rectmp[e];
    int dl = (int)(r.y & 0xFFu);
    int slot = atomicAdd(&cur[dl], 1);
    atomicAdd(&wsum[dl], h2f(r.x >> 16));
    uint_t src = r.x & 0xFFFFu;
    recw[slot] = r.x;
    reca[slot] = src | (r.y & 0xFFFF0000u);
  }
  __syncthreads();
  if (node < NN) dinv[node] = rsqrtf(1.f + wsum[t]);
  if (b == 0 && t == 0) {
    float s = 0.f;
    for (int j = 0; j < 64; ++j) s += scal[(size_t)j * 16];
    scal[1] = s / (float)NE;
  }
}

// ---------- fused GCN aggregate + LN + GAT node transform ----------
// 4 waves/block, 2 nodes/wave (half-wave per node, 2 cols/lane).
// LAYER 0 computes per-edge norms and caches them in normc; LAYER 1 reads
// them back sequentially (no dinv[src] gather).
template <int LAYER>
__global__ void __launch_bounds__(256) k_gcn_gat(
    const ushort_t* __restrict__ h16, const float* __restrict__ res,
    const float* __restrict__ dinv, const int* __restrict__ rs,
    const uint_t* __restrict__ recw, float* __restrict__ normc,
    const float* __restrict__ gb, const float* __restrict__ lg,
    const float* __restrict__ lb,
    const ushort_t* __restrict__ wg, const float* __restrict__ att_src,
    const float* __restrict__ att_dst,
    float* __restrict__ x2, ushort_t* __restrict__ xl,
    float* __restrict__ a_s, float* __restrict__ a_d) {
  __shared__ int ss[4][64];
  __shared__ float swt[4][64];
  __shared__ __align__(16) ushort_t xt[16][72];  // 144B row stride
  int w = threadIdx.x >> 6;
  int l = threadIdx.x & 63;
  int base = blockIdx.x * 8;
  int half = l >> 5, c = l & 31;   // half: 0=node A, 1=node B; cols 2c,2c+1
  int iA = base + 2 * w;
  int iB = iA + 1;
  int i = iA + half;
  float di = dinv[i];
  uint_t u0 = *(const uint_t*)&h16[(size_t)i * D + 2 * c];
  float dii = di * di;
  float acc0 = dii * b2f_lo(u0);
  float acc1 = dii * b2f_hi(u0);
  int kA = rs[iA], kA1 = rs[iA + 1];
  int kB = rs[iB], kB1 = rs[iB + 1];
  int sbase = half * 32;
  while (kA < kA1 || kB < kB1) {
    int cntA = min(32, kA1 - kA);
    int cntB = min(32, kB1 - kB);
    int myk = half ? kB : kA;
    int mycnt = half ? cntB : cntA;
    int src = 0; float wn = 0.f;
    if (c < mycnt) {
      uint_t r = recw[(size_t)(myk + c)];
      src = (int)(r & 0xFFFFu);
      if (LAYER == 0) {
        wn = dinv[src] * h2f(r >> 16) * di;
        normc[(size_t)(myk + c)] = wn;
      } else {
        wn = normc[(size_t)(myk + c)];
      }
    }
    ss[w][l] = src;
    swt[w][l] = wn;
    int nm = max(cntA, cntB);
    int j = 0;
    for (; j + 8 <= nm; j += 8) {
      int4 s4a = *(const int4*)&ss[w][sbase + j];
      int4 s4b = *(const int4*)&ss[w][sbase + j + 4];
      float4 w4a = *(const float4*)&swt[w][sbase + j];
      float4 w4b = *(const float4*)&swt[w][sbase + j + 4];
      uint_t ua = *(const uint_t*)&h16[(size_t)s4a.x * D + 2 * c];
      uint_t ub = *(const uint_t*)&h16[(size_t)s4a.y * D + 2 * c];
      uint_t uc = *(const uint_t*)&h16[(size_t)s4a.z * D + 2 * c];
      uint_t ud = *(const uint_t*)&h16[(size_t)s4a.w * D + 2 * c];
      uint_t ue = *(const uint_t*)&h16[(size_t)s4b.x * D + 2 * c];
      uint_t uf = *(const uint_t*)&h16[(size_t)s4b.y * D + 2 * c];
      uint_t ug = *(const uint_t*)&h16[(size_t)s4b.z * D + 2 * c];
      uint_t uh = *(const uint_t*)&h16[(size_t)s4b.w * D + 2 * c];
      acc0 = fmaf(w4a.x, b2f_lo(ua), acc0); acc1 = fmaf(w4a.x, b2f_hi(ua), acc1);
      acc0 = fmaf(w4a.y, b2f_lo(ub), acc0); acc1 = fmaf(w4a.y, b2f_hi(ub), acc1);
      acc0 = fmaf(w4a.z, b2f_lo(uc), acc0); acc1 = fmaf(w4a.z, b2f_hi(uc), acc1);
      acc0 = fmaf(w4a.w, b2f_lo(ud), acc0); acc1 = fmaf(w4a.w, b2f_hi(ud), acc1);
      acc0 = fmaf(w4b.x, b2f_lo(ue), acc0); acc1 = fmaf(w4b.x, b2f_hi(ue), acc1);
      acc0 = fmaf(w4b.y, b2f_lo(uf), acc0); acc1 = fmaf(w4b.y, b2f_hi(uf), acc1);
      acc0 = fmaf(w4b.z, b2f_lo(ug), acc0); acc1 = fmaf(w4b.z, b2f_hi(ug), acc1);
      acc0 = fmaf(w4b.w, b2f_lo(uh), acc0); acc1 = fmaf(w4b.w, b2f_hi(uh), acc1);
    }
    for (; j + 4 <= nm; j += 4) {
      int4 s4 = *(const int4*)&ss[w][sbase + j];
      float4 w4 = *(const float4*)&swt[w][sbase + j];
      uint_t ua = *(const uint_t*)&h16[(size_t)s4.x * D + 2 * c];
      uint_t ub = *(const uint_t*)&h16[(size_t)s4.y * D + 2 * c];
      uint_t uc = *(const uint_t*)&h16[(size_t)s4.z * D + 2 * c];
      uint_t ud = *(const uint_t*)&h16[(size_t)s4.w * D + 2 * c];
      acc0 = fmaf(w4.x, b2f_lo(ua), acc0); acc1 = fmaf(w4.x, b2f_hi(ua), acc1);
      acc0 = fmaf(w4.y, b2f_lo(ub), acc0); acc1 = fmaf(w4.y, b2f_hi(ub), acc1);
      acc0 = fmaf(w4.z, b2f_lo(uc), acc0); acc1 = fmaf(w4.z, b2f_hi(uc), acc1);
      acc0 = fmaf(w4.w, b2f_lo(ud), acc0); acc1 = fmaf(w4.w, b2f_hi(ud), acc1);
    }
    for (; j < nm; ++j) {
      int s1 = ss[w][sbase + j];
      float w1 = swt[w][sbase + j];
      uint_t u = *(const uint_t*)&h16[(size_t)s1 * D + 2 * c];
      acc0 = fmaf(w1, b2f_lo(u), acc0);
      acc1 = fmaf(w1, b2f_hi(u), acc1);
    }
    kA += cntA; kB += cntB;
  }
  float2 gb2 = *(const float2*)&gb[2 * c];
  float2 lg2 = *(const float2*)&lg[2 * c];
  float2 lb2 = *(const float2*)&lb[2 * c];
  float2 rs2 = *(const float2*)&res[(size_t)i * D + 2 * c];
  float x0 = silu_f(acc0 + gb2.x) + rs2.x;
  float x1 = silu_f(acc1 + gb2.y) + rs2.y;
  float mu = half_sum32(x0 + x1) * (1.f / 64.f);
  float d0 = x0 - mu, d1 = x1 - mu;
  float var = half_sum32(d0 * d0 + d1 * d1) * (1.f / 64.f);
  float rinv = rsqrtf(var + EPS);
  float o0 = d0 * rinv * lg2.x + lb2.x;
  float o1 = d1 * rinv * lg2.y + lb2.y;
  float2 o2; o2.x = o0; o2.y = o1;
  *(float2*)&x2[(size_t)i * D + 2 * c] = o2;
  uint_t pk = (uint_t)f2b(o0) | ((uint_t)f2b(o1) << 16);
  *(uint_t*)&xt[2 * w + half][2 * c] = pk;
  {
    ushort_t* xz = &xt[8][0];
    for (int e = threadIdx.x; e < 8 * 72; e += 256) xz[e] = 0;
  }
  __syncthreads();
  // GAT node transform: xl = bf16(x2) @ Wg (wave w owns col-tile t=w)
  int t = w;
  int q = l >> 4, cn = l & 15;
  bf16x8 a0 = *(const bf16x8*)&xt[cn][q * 8];
  bf16x8 a1 = *(const bf16x8*)&xt[cn][q * 8 + 32];
  bf16x8 b0 = *(const bf16x8*)&wg[(size_t)((0 * 4 + t) * 512 + l * 8)];
  bf16x8 b1 = *(const bf16x8*)&wg[(size_t)((1 * 4 + t) * 512 + l * 8)];
  f32x4 z = {0.f, 0.f, 0.f, 0.f};
  f32x4 acc = __builtin_amdgcn_mfma_f32_16x16x32_bf16(a0, b0, z, 0, 0, 0);
  acc = __builtin_amdgcn_mfma_f32_16x16x32_bf16(a1, b1, acc, 0, 0, 0);
  if (q < 2) {  // only rows 0..7 are real nodes
    float av = att_src[t * 16 + cn];
    float dv = att_dst[t * 16 + cn];
#pragma unroll
    for (int r = 0; r < 4; ++r) {
      size_t row = (size_t)base + q * 4 + r;
      xl[row * D + t * 16 + cn] = f2b(acc[r]);
      float vs = group_sum16(acc[r] * av);
      float vd = group_sum16(acc[r] * dv);
      if (cn == 0) {
        a_s[row * 4 + t] = vs;
        a_d[row * 4 + t] = vd;
      }
    }
  }
}

// ---------- fused GAT aggregate (+ optional next-layer dual GEMM) ----------
template <int FUSE>
__global__ void __launch_bounds__(256) k_gat_fin(
    const ushort_t* __restrict__ xl16, const float* __restrict__ x2,
    const float* __restrict__ a_s, const float* __restrict__ a_d,
    const int* __restrict__ rs, const uint_t* __restrict__ reca,
    const float* __restrict__ wea, const float* __restrict__ scal,
    const float* __restrict__ bg,
    const ushort_t* __restrict__ wd, const float* __restrict__ b2,
    ushort_t* __restrict__ out1, float* __restrict__ out2,
    float* __restrict__ xout) {
  __shared__ int ss[4][64];
  __shared__ float el[4][4][68];
  __shared__ __align__(16) ushort_t xt[16][72];
  int w = threadIdx.x >> 6;
  int l = threadIdx.x & 63;
  int base = blockIdx.x * 8;
  int half = l >> 5, c = l & 31;
  int iA = base + 2 * w;
  int iB = iA + 1;
  int i = iA + half;
  int hh = c >> 3;  // head of cols 2c,2c+1
  float4 wv4 = *(const float4*)wea;
  float mean_attr = scal[1];
  float we_h = sel4(wv4.x, wv4.y, wv4.z, wv4.w, hh);
  float ad_h = a_d[(size_t)i * 4 + hh];
  float as_i = a_s[(size_t)i * 4 + hh];
  float eS = __expf(lrelu_f(as_i + ad_h + mean_attr * we_h));
  float s = eS;
  uint_t u0 = *(const uint_t*)&xl16[(size_t)i * D + 2 * c];
  float acc0 = eS * b2f_lo(u0);
  float acc1 = eS * b2f_hi(u0);
  float4 ad4 = *(const float4*)(a_d + (size_t)i * 4);
  int kA = rs[iA], kA1 = rs[iA + 1];
  int kB = rs[iB], kB1 = rs[iB + 1];
  int sbase = half * 32;
  while (kA < kA1 || kB < kB1) {
    int cntA = min(32, kA1 - kA);
    int cntB = min(32, kB1 - kB);
    int myk = half ? kB : kA;
    int mycnt = half ? cntB : cntA;
    int src = 0;
    float e0v = 0.f, e1v = 0.f, e2v = 0.f, e3v = 0.f;
    if (c < mycnt) {
      uint_t r = reca[(size_t)(myk + c)];
      src = (int)(r & 0xFFFFu);
      float ea = h2f(r >> 16);
      float4 as4 = *(const float4*)(a_s + (size_t)src * 4);
      e0v = __expf(lrelu_f(as4.x + fmaf(ea, wv4.x, ad4.x)));
      e1v = __expf(lrelu_f(as4.y + fmaf(ea, wv4.y, ad4.y)));
      e2v = __expf(lrelu_f(as4.z + fmaf(ea, wv4.z, ad4.z)));
      e3v = __expf(lrelu_f(as4.w + fmaf(ea, wv4.w, ad4.w)));
    }
    ss[w][l] = src;
    el[w][0][l] = e0v;
    el[w][1][l] = e1v;
    el[w][2][l] = e2v;
    el[w][3][l] = e3v;
    int nm = max(cntA, cntB);
    int j = 0;
    for (; j + 8 <= nm; j += 8) {
      int4 s4a = *(const int4*)&ss[w][sbase + j];
      int4 s4b = *(const int4*)&ss[w][sbase + j + 4];
      float4 e4a = *(const float4*)&el[w][hh][sbase + j];
      float4 e4b = *(const float4*)&el[w][hh][sbase + j + 4];
      uint_t ua = *(const uint_t*)&xl16[(size_t)s4a.x * D + 2 * c];
      uint_t ub = *(const uint_t*)&xl16[(size_t)s4a.y * D + 2 * c];
      uint_t uc = *(const uint_t*)&xl16[(size_t)s4a.z * D + 2 * c];
      uint_t ud = *(const uint_t*)&xl16[(size_t)s4a.w * D + 2 * c];
      uint_t ue = *(const uint_t*)&xl16[(size_t)s4b.x * D + 2 * c];
      uint_t uf = *(const uint_t*)&xl16[(size_t)s4b.y * D + 2 * c];
      uint_t ug = *(const uint_t*)&xl16[(size_t)s4b.z * D + 2 * c];
      uint_t uh = *(const uint_t*)&xl16[(size_t)s4b.w * D + 2 * c];
      acc0 = fmaf(e4a.x, b2f_lo(ua), acc0); acc1 = fmaf(e4a.x, b2f_hi(ua), acc1);
      acc0 = fmaf(e4a.y, b2f_lo(ub), acc0); acc1 = fmaf(e4a.y, b2f_hi(ub), acc1);
      acc0 = fmaf(e4a.z, b2f_lo(uc), acc0); acc1 = fmaf(e4a.z, b2f_hi(uc), acc1);
      acc0 = fmaf(e4a.w, b2f_lo(ud), acc0); acc1 = fmaf(e4a.w, b2f_hi(ud), acc1);
      acc0 = fmaf(e4b.x, b2f_lo(ue), acc0); acc1 = fmaf(e4b.x, b2f_hi(ue), acc1);
      acc0 = fmaf(e4b.y, b2f_lo(uf), acc0); acc1 = fmaf(e4b.y, b2f_hi(uf), acc1);
      acc0 = fmaf(e4b.z, b2f_lo(ug), acc0); acc1 = fmaf(e4b.z, b2f_hi(ug), acc1);
      acc0 = fmaf(e4b.w, b2f_lo(uh), acc0); acc1 = fmaf(e4b.w, b2f_hi(uh), acc1);
      s += (e4a.x + e4a.y) + (e4a.z + e4a.w);
      s += (e4b.x + e4b.y) + (e4b.z + e4b.w);
    }
    for (; j + 4 <= nm; j += 4) {
      int4 s4 = *(const int4*)&ss[w][sbase + j];
      float4 e4 = *(const float4*)&el[w][hh][sbase + j];
      uint_t ua = *(const uint_t*)&xl16[(size_t)s4.x * D + 2 * c];
      uint_t ub = *(const uint_t*)&xl16[(size_t)s4.y * D + 2 * c];
      uint_t uc = *(const uint_t*)&xl16[(size_t)s4.z * D + 2 * c];
      uint_t ud = *(const uint_t*)&xl16[(size_t)s4.w * D + 2 * c];
      acc0 = fmaf(e4.x, b2f_lo(ua), acc0); acc1 = fmaf(e4.x, b2f_hi(ua), acc1);
      acc0 = fmaf(e4.y, b2f_lo(ub), acc0); acc1 = fmaf(e4.y, b2f_hi(ub), acc1);
      acc0 = fmaf(e4.z, b2f_lo(uc), acc0); acc1 = fmaf(e4.z, b2f_hi(uc), acc1);
      acc0 = fmaf(e4.w, b2f_lo(ud), acc0); acc1 = fmaf(e4.w, b2f_hi(ud), acc1);
      s += (e4.x + e4.y) + (e4.z + e4.w);
    }
    for (; j < nm; ++j) {
      int s1 = ss[w][sbase + j];
      float e1 = el[w][hh][sbase + j];
      uint_t u = *(const uint_t*)&xl16[(size_t)s1 * D + 2 * c];
      acc0 = fmaf(e1, b2f_lo(u), acc0);
      acc1 = fmaf(e1, b2f_hi(u), acc1);
      s += e1;
    }
    kA += cntA; kB += cntB;
  }
  float2 bg2 = *(const float2*)&bg[2 * c];
  float rcp = 1.f / (s + 1e-16f);
  float o0 = acc0 * rcp + bg2.x;
  float o1 = acc1 * rcp + bg2.y;
  float2 x22 = *(const float2*)&x2[(size_t)i * D + 2 * c];
  float v0 = silu_f(o0) + x22.x;
  float v1 = silu_f(o1) + x22.y;
  if (FUSE) {
    // next layer's dual GEMM straight from LDS (xmid never materialized)
    uint_t pk = (uint_t)f2b(v0) | ((uint_t)f2b(v1) << 16);
    *(uint_t*)&xt[2 * w + half][2 * c] = pk;
    {
      ushort_t* xz = &xt[8][0];
      for (int e = threadIdx.x; e < 8 * 72; e += 256) xz[e] = 0;
    }
    __syncthreads();
    int t = w;
    int q = l >> 4, cn = l & 15;
    bf16x8 a0 = *(const bf16x8*)&xt[cn][q * 8];
    bf16x8 a1 = *(const bf16x8*)&xt[cn][q * 8 + 32];
#pragma unroll
    for (int m = 0; m < 2; ++m) {
      bf16x8 b0 = *(const bf16x8*)&wd[(size_t)((m * 8 + 0 * 4 + t) * 512 + l * 8)];
      bf16x8 b1 = *(const bf16x8*)&wd[(size_t)((m * 8 + 1 * 4 + t) * 512 + l * 8)];
      f32x4 z = {0.f, 0.f, 0.f, 0.f};
      f32x4 acc = __builtin_amdgcn_mfma_f32_16x16x32_bf16(a0, b0, z, 0, 0, 0);
      acc = __builtin_amdgcn_mfma_f32_16x16x32_bf16(a1, b1, acc, 0, 0, 0);
      if (q < 2) {
        float bb = (m == 1) ? b2[t * 16 + cn] : 0.f;
#pragma unroll
        for (int r = 0; r < 4; ++r) {
          size_t row = (size_t)base + q * 4 + r;
          if (m == 0)
            out1[row * D + t * 16 + cn] = f2b(acc[r]);
          else
            out2[row * D + t * 16 + cn] = acc[r] + bb;
        }
      }
    }
  } else {
    float2 v2; v2.x = v0; v2.y = v1;
    *(float2*)&xout[(size_t)i * D + 2 * c] = v2;
  }
}

// ---------- launch ----------

extern "C" void kernel_launch(void* const* d_in, const int* in_sizes, int n_in,
                              void* d_out, int out_size, void* d_ws, size_t ws_size,
                              hipStream_t stream) {
  (void)in_sizes; (void)n_in; (void)out_size; (void)ws_size;
  const float* x  = (const float*)d_in[0];
  const int*   ei = (const int*)d_in[1];
  const float* ew = (const float*)d_in[2];
  const float* ea = (const float*)d_in[3];
  const float* P[2][12];
  for (int l = 0; l < 2; ++l)
    for (int j = 0; j < 12; ++j) P[l][j] = (const float*)d_in[4 + l * 12 + j];

  float* W = (float*)d_ws;
  const size_t o_rs    = 0;                          // NN+16 ints
  const size_t o_dinv  = o_rs + NN + 16;             // NN
  const size_t o_wea   = o_dinv + NN;                // 16 (wea2[8] used)
  const size_t o_scal  = o_wea + 16;                 // 1024
  const size_t o_bsum  = o_scal + 1024;              // 256
  const size_t o_hist  = o_bsum + 256;               // STOT ints
  const size_t o_recw  = o_hist + STOT;              // NE uint
  const size_t o_reca  = o_recw + NE;                // NE uint
  const size_t o_norm  = o_reca + NE;                // NE float (cached norms)
  const size_t o_rtmp  = o_norm + NE;                // NE uint2
  const size_t o_h16   = o_rtmp + (size_t)NE * 2;    // NN*D ushort
  const size_t o_xl16  = o_h16 + (size_t)NN * D / 2;
  const size_t o_res   = o_xl16 + (size_t)NN * D / 2;
  const size_t o_x2    = o_res + (size_t)NN * D;
  const size_t o_as    = o_x2 + (size_t)NN * D;      // NN*4
  const size_t o_ad    = o_as + (size_t)NN * 4;      // NN*4
  const size_t o_wg16  = o_ad + (size_t)NN * 4;      // 2*4096 ushort (16KB)
  const size_t o_wd16  = o_wg16 + 4096;              // 8192 ushort (16KB)

  int*      rs    = (int*)(W + o_rs);
  float*    dinv  = W + o_dinv;
  float*    wea2  = W + o_wea;
  float*    scal  = W + o_scal;
  int*      bsum  = (int*)(W + o_bsum);
  int*      histG = (int*)(W + o_hist);
  uint_t*   recw  = (uint_t*)(W + o_recw);
  uint_t*   reca  = (uint_t*)(W + o_reca);
  float*    normc = W + o_norm;
  uint2*    rtmp  = (uint2*)(W + o_rtmp);
  ushort_t* h16   = (ushort_t*)(W + o_h16);
  ushort_t* xl16  = (ushort_t*)(W + o_xl16);
  float*    resb  = W + o_res;
  float*    x2b   = W + o_x2;
  float*    asb   = W + o_as;
  float*    adb   = W + o_ad;
  ushort_t* wg16  = (ushort_t*)(W + o_wg16);
  ushort_t* wd16  = (ushort_t*)(W + o_wd16);

  const int B = 256;
  const int gSf = NBIN + (NT + 3) / 4;  // sort buckets + layer0 gemm blocks
  const int gN2 = NN / 8;               // 8 nodes per block (4 waves x 2)

  k_hist<<<NB1, B, 0, stream>>>(ei, histG);
  k_scanA<<<SBLK + 1, B, 0, stream>>>(histG, bsum, scal,
                                      P[0][6], P[1][6], P[1][0], P[1][2],
                                      P[0][11], P[0][10], P[1][11], P[1][10],
                                      wg16, wd16, wea2);
  k_part<<<NB1, B, 0, stream>>>(ei, ew, ea, histG, bsum, rtmp, scal);
  k_sfing<<<gSf, B, 0, stream>>>(rtmp, histG, bsum, recw, reca, rs, dinv, scal,
                                 x, P[0][0], P[0][2], P[0][3], h16, resb);

  // layer 0
  k_gcn_gat<0><<<gN2, B, 0, stream>>>(h16, resb, dinv, rs, recw, normc,
                                      P[0][1], P[0][4], P[0][5],
                                      wg16, P[0][8], P[0][9],
                                      x2b, xl16, asb, adb);
  k_gat_fin<1><<<gN2, B, 0, stream>>>(xl16, x2b, asb, adb, rs, reca,
                                      wea2, scal, P[0][7],
                                      wd16, P[1][3], h16, resb, nullptr);
  // layer 1
  k_gcn_gat<1><<<gN2, B, 0, stream>>>(h16, resb, dinv, rs, recw, normc,
                                      P[1][1], P[1][4], P[1][5],
                                      wg16 + 4096, P[1][8], P[1][9],
                                      x2b, xl16, asb, adb);
  k_gat_fin<0><<<gN2, B, 0, stream>>>(xl16, x2b, asb, adb, rs, reca,
                                      wea2 + 4, scal, P[1][7],
                                      nullptr, nullptr, nullptr, nullptr,
                                      (float*)d_out);
}